// Round 6
// baseline (421.661 us; speedup 1.0000x reference)
//
#include <hip/hip_runtime.h>
#include <math.h>

// ---------------------------------------------------------------------------
// TimeMix (RWKV-6 vision block) — round 15: k_wkv_intra reshaped to 2 chunks
// per block with 3 LDS tiles (48KB): 768 blocks = exactly 3/CU resident ->
// single scheduling round (kills the tail-round latency exposure diagnosed
// in R14), cross-chunk GLDS prefetch hides staging under compute.
// B=8, T=1024, C=768, H=12.
// ---------------------------------------------------------------------------

#define EPI_NONE 0
#define EPI_TANH 1
#define EPI_RELU 2
#define EPI_BIAS 3

typedef float f32x4 __attribute__((ext_vector_type(4)));
typedef __bf16 bf16x8 __attribute__((ext_vector_type(8)));

__device__ __forceinline__ ushort f2bf(float x) {
  unsigned u = __float_as_uint(x);
  return (ushort)((u + 0x7fffu + ((u >> 16) & 1u)) >> 16);
}

#define GLDS16(gp, lp)                                                   \
  __builtin_amdgcn_global_load_lds(                                      \
      (const __attribute__((address_space(1))) void*)(gp),               \
      (__attribute__((address_space(3))) void*)(lp), 16, 0, 0)

// ---------------------------------------------------------------- qshift ---
__global__ __launch_bounds__(256) void k_qshift(
    const float* __restrict__ x, const float* __restrict__ maa_x,
    ushort* __restrict__ xxx_bf,
    int B, int T, int C, int ph, int pw) {
  long idx = (long)blockIdx.x * blockDim.x + threadIdx.x;
  long total = (long)B * T * C;
  if (idx >= total) return;
  int c = (int)(idx % C);
  long bt = idx / C;
  int t = (int)(bt % T);
  int quarter = (c & 63) >> 4;
  int hh = t / pw;
  int ww = t - hh * pw;
  long rowbase = (bt - t) * C;
  float sval = 0.f;
  int st = -1;
  if (quarter == 0)      { if (ww >= 1)      st = t - 1;  }
  else if (quarter == 1) { if (ww < pw - 1)  st = t + 1;  }
  else if (quarter == 2) { if (hh >= 1)      st = t - pw; }
  else                   { if (hh < ph - 1)  st = t + pw; }
  if (st >= 0) sval = x[rowbase + (long)st * C + c];
  float xval = x[idx];
  float d = sval - xval;
  xxx_bf[idx] = f2bf(xval + d * maa_x[c]);
}

// ----------------- fused weight transposes -> bf16 (one launch) ------------
__global__ __launch_bounds__(256) void k_wprep(
    const float* __restrict__ w1, const float* __restrict__ w2,
    const float* __restrict__ dw1, const float* __restrict__ dw2,
    ushort* __restrict__ maa1T, ushort* __restrict__ w2T,
    ushort* __restrict__ w1dT, ushort* __restrict__ w2dT) {
  int idx = blockIdx.x * 256 + threadIdx.x;
  if (idx < 196608) {
    int n = idx / 768, k = idx - n * 768;
    maa1T[idx] = f2bf(n < 160 ? w1[(size_t)k * 160 + n] : 0.f);
  } else if (idx < 196608 + 122880) {
    int j = idx - 196608;
    int c = j / 160, kk = j - c * 160;
    w2T[j] = f2bf(w2[(size_t)kk * 768 + c]);
  } else if (idx < 196608 + 122880 + 98304) {
    int j = idx - (196608 + 122880);
    int n = j / 768, k = j - n * 768;
    w1dT[j] = f2bf(n < 64 ? dw1[(size_t)k * 64 + n] : 0.f);
  } else {
    int j = idx - (196608 + 122880 + 98304);
    int n = j >> 6, k = j & 63;
    w2dT[j] = f2bf(dw2[(size_t)k * 768 + n]);
  }
}

// --------------------------- mix5 on MFMA, no LDS, no barriers -------------
__global__ __launch_bounds__(256) void k_mix5m(
    const ushort* __restrict__ t5b, const ushort* __restrict__ w2T,
    const float* __restrict__ x,
    const float* __restrict__ maa_w, const float* __restrict__ maa_k,
    const float* __restrict__ maa_v, const float* __restrict__ maa_r,
    const float* __restrict__ maa_g,
    ushort* __restrict__ xw, ushort* __restrict__ xk, ushort* __restrict__ xvb,
    ushort* __restrict__ xr, ushort* __restrict__ xg,
    int C, int T, int ph, int pw) {
  int tid = threadIdx.x;
  int lane = tid & 63, wid = tid >> 6;
  int m0 = blockIdx.y * 64, n0 = blockIdx.x * 128;
  int lm = lane & 15, lk = (lane >> 4) * 8;
  int rq = (lane >> 4) * 4;
  const ushort* ap = t5b + (size_t)(m0 + wid * 16 + lm) * 160 + lk;

  int stq[4][4];
#pragma unroll
  for (int q = 0; q < 4; q++) {
    int mr = m0 + wid * 16 + rq + q;
    int t = mr % T;
    int hh = t / pw, ww = t - hh * pw;
    stq[q][0] = (ww >= 1)      ? mr - 1  : -1;
    stq[q][1] = (ww < pw - 1)  ? mr + 1  : -1;
    stq[q][2] = (hh >= 1)      ? mr - pw : -1;
    stq[q][3] = (hh < ph - 1)  ? mr + pw : -1;
  }

  float xh[8][4], dh[8][4];
#pragma unroll
  for (int j = 0; j < 8; j++)
#pragma unroll
    for (int q = 0; q < 4; q++) {
      int mr = m0 + wid * 16 + rq + q;
      int col = n0 + j * 16 + lm;
      float xv = x[(size_t)mr * C + col];
      int sr = stq[q][j & 3];
      float sv = (sr >= 0) ? x[(size_t)sr * C + col] : 0.f;
      xh[j][q] = xv;
      dh[j][q] = sv - xv;
    }

#pragma unroll
  for (int f = 0; f < 5; f++) {
    bf16x8 af = *(const bf16x8*)(ap + f * 32);
    f32x4 acc[8];
#pragma unroll
    for (int j = 0; j < 8; j++) {
      bf16x8 bfj = *(const bf16x8*)(w2T +
          (size_t)(n0 + j * 16 + lm) * 160 + f * 32 + lk);
      acc[j] = __builtin_amdgcn_mfma_f32_16x16x32_bf16(
          af, bfj, (f32x4){0.f, 0.f, 0.f, 0.f}, 0, 0, 0);
    }
    const float* maa_f = (f == 0) ? maa_w : (f == 1) ? maa_k
                        : (f == 2) ? maa_v : (f == 3) ? maa_r : maa_g;
    ushort* dst = (f == 0) ? xw : (f == 1) ? xk
                 : (f == 2) ? xvb : (f == 3) ? xr : xg;
#pragma unroll
    for (int j = 0; j < 8; j++) {
      float mf = maa_f[n0 + j * 16 + lm];
#pragma unroll
      for (int q = 0; q < 4; q++) {
        size_t off = (size_t)(m0 + wid * 16 + rq + q) * C + (n0 + j * 16 + lm);
        dst[off] = f2bf(xh[j][q] + dh[j][q] * (mf + acc[j][q]));
      }
    }
  }
}

// -------------------------------------------- fp32 -> bf16 cvt (5 arrays) --
__global__ __launch_bounds__(256) void k_cvt5(
    const float* __restrict__ s0, const float* __restrict__ s1,
    const float* __restrict__ s2, const float* __restrict__ s3,
    const float* __restrict__ s4,
    ushort* __restrict__ d0, ushort* __restrict__ d1,
    ushort* __restrict__ d2, ushort* __restrict__ d3,
    ushort* __restrict__ d4, int n) {
  const float* s;
  ushort* d;
  switch (blockIdx.y) {
    case 0: s = s0; d = d0; break;
    case 1: s = s1; d = d1; break;
    case 2: s = s2; d = d2; break;
    case 3: s = s3; d = d3; break;
    default: s = s4; d = d4; break;
  }
  int i = (blockIdx.x * 256 + threadIdx.x) * 4;
  if (i >= n) return;
  float4 v = *(const float4*)(s + i);
  ushort4 o;
  o.x = f2bf(v.x); o.y = f2bf(v.y); o.z = f2bf(v.z); o.w = f2bf(v.w);
  *(ushort4*)(d + i) = o;
}

// ----------------------------------------------------- bf16 MFMA GEMM ------
template <int EPI, bool NMASK, bool OBF16>
__global__ __launch_bounds__(256) void k_gemm_bf(
    const ushort* __restrict__ A, const ushort* __restrict__ W,
    const float* __restrict__ bias, void* __restrict__ Cm,
    int M, int N, int K) {
  __shared__ ushort Al[128 * 64];
  __shared__ ushort Bl[128 * 64];
  int nwg = gridDim.x * gridDim.y;
  int bid = blockIdx.y * gridDim.x + blockIdx.x;
  int swz = (nwg & 7) == 0 ? ((bid & 7) * (nwg >> 3) + (bid >> 3)) : bid;
  int bx = swz % gridDim.x, by = swz / gridDim.x;
  int m0 = by * 128, n0 = bx * 128;
  int tid = threadIdx.x;
  int lane = tid & 63, wave = tid >> 6;
  int wm = (wave >> 1) * 64, wn = (wave & 1) * 64;
  int lm = lane & 15, g = lane >> 4;
  f32x4 acc[4][4];
#pragma unroll
  for (int i = 0; i < 4; i++)
#pragma unroll
    for (int j = 0; j < 4; j++) acc[i][j] = (f32x4){0.f, 0.f, 0.f, 0.f};

  for (int k0 = 0; k0 < K; k0 += 64) {
#pragma unroll
    for (int i = 0; i < 4; i++) {
      int cid = tid + i * 256;             // 0..1023 16B-chunks
      int row = cid >> 3, p = cid & 7;
      int cq = p ^ (row & 7);
      GLDS16(A + (size_t)(m0 + row) * K + k0 + cq * 8, Al + cid * 8);
      GLDS16(W + (size_t)(n0 + row) * K + k0 + cq * 8, Bl + cid * 8);
    }
    __syncthreads();
#pragma unroll
    for (int s = 0; s < 2; s++) {
      bf16x8 af[4], bf[4];
#pragma unroll
      for (int i = 0; i < 4; i++) {
        int r = wm + i * 16 + lm;
        af[i] = *(const bf16x8*)&Al[r * 64 + (((s * 4 + g) ^ (r & 7)) * 8)];
        int rb = wn + i * 16 + lm;
        bf[i] = *(const bf16x8*)&Bl[rb * 64 + (((s * 4 + g) ^ (rb & 7)) * 8)];
      }
#pragma unroll
      for (int i = 0; i < 4; i++)
#pragma unroll
        for (int j = 0; j < 4; j++)
          acc[i][j] = __builtin_amdgcn_mfma_f32_16x16x32_bf16(
              af[i], bf[j], acc[i][j], 0, 0, 0);
    }
    __syncthreads();
  }
  int rq = (lane >> 4) * 4;
#pragma unroll
  for (int i = 0; i < 4; i++) {
#pragma unroll
    for (int j = 0; j < 4; j++) {
      int gn = n0 + wn + j * 16 + lm;
      if (NMASK && gn >= N) continue;
      float bv = (EPI == EPI_BIAS) ? bias[gn] : 0.f;
#pragma unroll
      for (int q = 0; q < 4; q++) {
        int gm = m0 + wm + i * 16 + rq + q;
        float val = acc[i][j][q];
        if (EPI == EPI_BIAS) val += bv;
        if (EPI == EPI_RELU) val = fmaxf(val, 0.f);
        if (EPI == EPI_TANH) val = tanhf(val);
        if (OBF16) ((ushort*)Cm)[(size_t)gm * N + gn] = f2bf(val);
        else       ((float*)Cm)[(size_t)gm * N + gn] = val;
      }
    }
  }
}

// --------------------------------- batched 4-projection bf16 MFMA GEMM -----
__global__ __launch_bounds__(256) void k_proj4(
    const ushort* __restrict__ A0, const ushort* __restrict__ A1,
    const ushort* __restrict__ A2, const ushort* __restrict__ A3,
    const ushort* __restrict__ W0, const ushort* __restrict__ W1,
    const ushort* __restrict__ W2, const ushort* __restrict__ W3,
    float* __restrict__ C0, float* __restrict__ C1,
    float* __restrict__ C2, float* __restrict__ C3,
    int M, int N, int K) {
  int nwg = gridDim.x;                       // 1536, %8==0
  int bid = blockIdx.x;
  int swz = (bid & 7) * (nwg >> 3) + (bid >> 3);
  int nxt = N / 128;                         // 6
  int per_z = (M / 128) * nxt;               // 384
  int z = swz / per_z;
  int rem = swz - z * per_z;
  int my = rem / nxt, nx = rem - my * nxt;
  const ushort* A = (z == 0) ? A0 : (z == 1) ? A1 : (z == 2) ? A2 : A3;
  const ushort* W = (z == 0) ? W0 : (z == 1) ? W1 : (z == 2) ? W2 : W3;
  float* Cm       = (z == 0) ? C0 : (z == 1) ? C1 : (z == 2) ? C2 : C3;
  __shared__ ushort Al[128 * 64];
  __shared__ ushort Bl[128 * 64];
  int tid = threadIdx.x;
  int m0 = my * 128, n0 = nx * 128;
  int lane = tid & 63, wave = tid >> 6;
  int wm = (wave >> 1) * 64, wn = (wave & 1) * 64;
  int lm = lane & 15, g = lane >> 4;
  f32x4 acc[4][4];
#pragma unroll
  for (int i = 0; i < 4; i++)
#pragma unroll
    for (int j = 0; j < 4; j++) acc[i][j] = (f32x4){0.f, 0.f, 0.f, 0.f};

  for (int k0 = 0; k0 < K; k0 += 64) {
#pragma unroll
    for (int i = 0; i < 4; i++) {
      int cid = tid + i * 256;
      int row = cid >> 3, p = cid & 7;
      int cq = p ^ (row & 7);
      GLDS16(A + (size_t)(m0 + row) * K + k0 + cq * 8, Al + cid * 8);
      GLDS16(W + (size_t)(n0 + row) * K + k0 + cq * 8, Bl + cid * 8);
    }
    __syncthreads();
#pragma unroll
    for (int s = 0; s < 2; s++) {
      bf16x8 af[4], bf[4];
#pragma unroll
      for (int i = 0; i < 4; i++) {
        int r = wm + i * 16 + lm;
        af[i] = *(const bf16x8*)&Al[r * 64 + (((s * 4 + g) ^ (r & 7)) * 8)];
        int rb = wn + i * 16 + lm;
        bf[i] = *(const bf16x8*)&Bl[rb * 64 + (((s * 4 + g) ^ (rb & 7)) * 8)];
      }
#pragma unroll
      for (int i = 0; i < 4; i++)
#pragma unroll
        for (int j = 0; j < 4; j++)
          acc[i][j] = __builtin_amdgcn_mfma_f32_16x16x32_bf16(
              af[i], bf[j], acc[i][j], 0, 0, 0);
    }
    __syncthreads();
  }
  bool relu = (z == 3);
  int rq = (lane >> 4) * 4;
#pragma unroll
  for (int i = 0; i < 4; i++) {
#pragma unroll
    for (int j = 0; j < 4; j++) {
      int gn = n0 + wn + j * 16 + lm;
#pragma unroll
      for (int q = 0; q < 4; q++) {
        int gm = m0 + wm + i * 16 + rq + q;
        float val = acc[i][j][q];
        if (relu) val = fmaxf(val, 0.f);
        Cm[(size_t)gm * N + gn] = val;
      }
    }
  }
}

// ------------------------------------------------- chunked WKV: phase pre --
__global__ __launch_bounds__(64) void k_wkv_pre(
    const float* __restrict__ r, const float* __restrict__ k,
    const float* __restrict__ w, const float* __restrict__ u,
    float* __restrict__ rt, float* __restrict__ kt,
    float* __restrict__ aL, float* __restrict__ pdiag,
    int B, int T, int C, int H, int L) {
  __shared__ float pls[64 * 65];
  int nch = T / L;
  int blk = blockIdx.x;
  int bh = blk / nch, c = blk - bh * nch;
  int b = bh / H, h = bh - b * H;
  int j = threadIdx.x;
  float uj = u[h * 64 + j];
  float cum = 0.f;
  long base = ((long)b * T + (long)c * L) * C + h * 64 + j;
  for (int tau = 0; tau < L; tau++) {
    long off = base + (long)tau * C;
    float wv = w[off];
    float rv = r[off];
    float kv = k[off];
    float e = expf(wv);
    rt[off] = rv * expf(-cum);
    cum += e;
    kt[off] = kv * expf(cum);
    pls[tau * 65 + j] = rv * uj * kv;
  }
  aL[((long)bh * nch + c) * 64 + j] = expf(-cum);
  __syncthreads();
  float s0 = 0.f, s1 = 0.f, s2 = 0.f, s3 = 0.f;
#pragma unroll
  for (int q = 0; q < 16; q++) {
    float4 p4 = *(const float4*)(pls + j * 65 + q * 4);
    s0 += p4.x; s1 += p4.y; s2 += p4.z; s3 += p4.w;
  }
  pdiag[(long)bh * T + c * L + j] = (s0 + s1) + (s2 + s3);
}

// --------------------------------------- chunked WKV: per-chunk KV outer ---
__global__ __launch_bounds__(256) void k_wkv_kv(
    const float* __restrict__ kt, const float* __restrict__ v,
    float* __restrict__ kvb, int B, int T, int C, int H, int L) {
  int nch = T / L;
  int blk = blockIdx.x;
  int bh = blk / nch, c = blk - bh * nch;
  int b = bh / H, h = bh - b * H;
  __shared__ float Ks[64 * 64];
  __shared__ float Vs[64 * 64];
  int tid = threadIdx.x;
  int lane = tid & 63, jg = tid >> 6;
  long cbase = ((long)b * T + (long)c * L) * C + h * 64;
#pragma unroll
  for (int i = 0; i < 4; i++) {
    int chunk = jg * 4 + i;
    int row = chunk * 4 + (lane >> 4);
    int cq = lane & 15;
    GLDS16(kt + cbase + (long)row * C + cq * 4, Ks + chunk * 256);
    GLDS16(v + cbase + (long)row * C + cq * 4, Vs + chunk * 256);
  }
  __syncthreads();
  float acc[16];
#pragma unroll
  for (int q = 0; q < 16; q++) acc[q] = 0.f;
  for (int s = 0; s < 64; s++) {
    float vi = Vs[s * 64 + lane];
#pragma unroll
    for (int q4 = 0; q4 < 4; q4++) {
      float4 kk = *(const float4*)(Ks + s * 64 + jg * 16 + q4 * 4);
      acc[q4 * 4 + 0] = fmaf(kk.x, vi, acc[q4 * 4 + 0]);
      acc[q4 * 4 + 1] = fmaf(kk.y, vi, acc[q4 * 4 + 1]);
      acc[q4 * 4 + 2] = fmaf(kk.z, vi, acc[q4 * 4 + 2]);
      acc[q4 * 4 + 3] = fmaf(kk.w, vi, acc[q4 * 4 + 3]);
    }
  }
  float* out = kvb + ((long)bh * nch + c) * 4096;
#pragma unroll
  for (int q = 0; q < 16; q++) out[(jg * 16 + q) * 64 + lane] = acc[q];
}

// ---------------------------------------- chunked WKV: state prefix scan ---
__global__ __launch_bounds__(256) void k_wkv_scan(
    const float* __restrict__ kvb, const float* __restrict__ aL,
    float* __restrict__ Scb, int nch) {
  int bh = blockIdx.x >> 4;
  int e = ((blockIdx.x & 15) << 8) + threadIdx.x;   // 0..4095
  float S = 0.f;
  for (int c = 0; c < nch; c++) {
    long cb = ((long)bh * nch + c) * 4096 + e;
    Scb[cb] = S;
    S = aL[((long)bh * nch + c) * 64 + (e >> 6)] * (S + kvb[cb]);
  }
}

// ------------- chunked WKV: intra + inter + groupnorm*gate (fused) ---------
// 2 chunks/block, 3 tiles (48KB -> 3 blocks/CU, 768 blocks = 1 full round).
// TA: V -> Rt^T (both chunks)   TB: Kt -> P^T (both)   TC: Rt stage (both).
// Chunk B's Rt prefetches under chunk A's phase1/passA; Kt(B) under
// Rt^T-write/passB. 9 barriers per 2 chunks (was 12).
__global__ __launch_bounds__(256, 3) void k_wkv_intra(
    const float* __restrict__ rt, const float* __restrict__ kt,
    const float* __restrict__ v, const float* __restrict__ pdiag,
    const float* __restrict__ Scb, const float* __restrict__ g,
    const float* __restrict__ ln_w, const float* __restrict__ ln_b,
    ushort* __restrict__ z, int B, int T, int C, int H, int L) {
  int nch = T / L;            // 16
  int npair = nch >> 1;       // 8
  int blk = blockIdx.x;
  int bh = blk / npair, cp = blk - bh * npair;
  int c0 = cp * 2;
  int b = bh / H, h = bh - b * H;
  __shared__ float TA[64 * 64];
  __shared__ float TB[64 * 64];
  __shared__ float TC[64 * 64];
  int tid = threadIdx.x;
  int lane = tid & 63, wid = tid >> 6;
  int tau = lane;
  long cbase0 = ((long)b * T + (long)c0 * L) * C + h * 64;
  long cbase1 = cbase0 + (long)L * C;
  const float* scp0 = Scb + ((long)bh * nch + c0) * 4096;
  const float* scp1 = scp0 + 4096;
  int row0 = wid * 16 + ((lane >> 4) << 2);
  int c0v = (lane & 15) * 4;
  float4 lw4 = *(const float4*)(ln_w + h * 64 + c0v);
  float4 lb4 = *(const float4*)(ln_b + h * 64 + c0v);

  // ---- stage Rt(A)->TC (swizzled src), Kt(A)->TB ----
#pragma unroll
  for (int i = 0; i < 4; i++) {
    int chunk = wid * 4 + i;
    int row = chunk * 4 + (lane >> 4);
    int cq = lane & 15;
    GLDS16(rt + cbase0 + (long)row * C + ((cq ^ (row & 15)) * 4),
           TC + chunk * 256);
    GLDS16(kt + cbase0 + (long)row * C + cq * 4, TB + chunk * 256);
  }
  __syncthreads();                                           // b1

  float4 rreg[16];
#pragma unroll
  for (int q = 0; q < 16; q++)
    rreg[q] = *(const float4*)(TC + tau * 64 + ((q ^ (tau & 15)) * 4));
  float pd0 = pdiag[(long)bh * T + c0 * L + tau];
  float pd1 = pdiag[(long)bh * T + (c0 + 1) * L + tau];
  __syncthreads();                                           // b2 (TC free)

  // ---- async: V(A)->TA, Rt(B)->TC (land during phase1) ----
#pragma unroll
  for (int i = 0; i < 4; i++) {
    int chunk = wid * 4 + i;
    int row = chunk * 4 + (lane >> 4);
    int cq = lane & 15;
    GLDS16(v + cbase0 + (long)row * C + cq * 4, TA + chunk * 256);
    GLDS16(rt + cbase1 + (long)row * C + ((cq ^ (row & 15)) * 4),
           TC + chunk * 256);
  }

#define PHASE1(PD)                                                       \
  __builtin_amdgcn_s_setprio(1);                                         \
  _Pragma("unroll 2") for (int ss = 0; ss < 16; ss++) {                  \
    int s = wid * 16 + ss;                                               \
    float a0 = 0.f, a1 = 0.f, a2 = 0.f, a3 = 0.f;                        \
    _Pragma("unroll") for (int q = 0; q < 16; q++) {                     \
      float4 kk = *(const float4*)(TB + s * 64 + q * 4);                 \
      a0 = fmaf(rreg[q].x, kk.x, a0);                                    \
      a1 = fmaf(rreg[q].y, kk.y, a1);                                    \
      a2 = fmaf(rreg[q].z, kk.z, a2);                                    \
      a3 = fmaf(rreg[q].w, kk.w, a3);                                    \
    }                                                                    \
    float a = (a0 + a1) + (a2 + a3);                                     \
    TB[s * 64 + tau] = (s < tau) ? a : (s == tau ? (PD) : 0.f);          \
  }                                                                      \
  __builtin_amdgcn_s_setprio(0);

#define FMA1(A, P, V4)                 \
  A.x = fmaf(P, V4.x, A.x);            \
  A.y = fmaf(P, V4.y, A.y);            \
  A.z = fmaf(P, V4.z, A.z);            \
  A.w = fmaf(P, V4.w, A.w);

#define PASSA                                                            \
  __builtin_amdgcn_s_setprio(1);                                         \
  _Pragma("unroll 4") for (int j = 0; j < 64; j++) {                     \
    float4 pp = *(const float4*)(TB + j * 64 + row0);                    \
    float4 vv = *(const float4*)(TA + j * 64 + c0v);                     \
    FMA1(acc0, pp.x, vv);                                                \
    FMA1(acc1, pp.y, vv);                                                \
    FMA1(acc2, pp.z, vv);                                                \
    FMA1(acc3, pp.w, vv);                                                \
  }                                                                      \
  __builtin_amdgcn_s_setprio(0);

#define PASSB(SCP)                                                       \
  __builtin_amdgcn_s_setprio(1);                                         \
  _Pragma("unroll 4") for (int j = 0; j < 64; j++) {                     \
    float4 rr = *(const float4*)(TA + j * 64 + row0);                    \
    float4 ssv = *(const float4*)((SCP) + j * 64 + c0v);                 \
    FMA1(acc0, rr.x, ssv);                                               \
    FMA1(acc1, rr.y, ssv);                                               \
    FMA1(acc2, rr.z, ssv);                                               \
    FMA1(acc3, rr.w, ssv);                                               \
  }                                                                      \
  __builtin_amdgcn_s_setprio(0);

#define WRQ_ALL                                                          \
  {                                                                      \
    if (wid == 0) { WRQ(0) }                                             \
    else if (wid == 1) { WRQ(1) }                                        \
    else if (wid == 2) { WRQ(2) }                                        \
    else { WRQ(3) }                                                      \
  }
#define WRQ(SG)                                                          \
  _Pragma("unroll") for (int qq = 0; qq < 16; qq++) {                    \
    const float* rp = (const float*)&rreg[(SG) * 4 + (qq >> 2)];         \
    TA[((SG) * 16 + qq) * 64 + tau] = rp[qq & 3];                        \
  }

#define GNROW(A, m, CBASE)                                                 \
  {                                                                        \
    float s1 = (A.x + A.y) + (A.z + A.w);                                  \
    s1 += __shfl_xor(s1, 1, 64);                                           \
    s1 += __shfl_xor(s1, 2, 64);                                           \
    s1 += __shfl_xor(s1, 4, 64);                                           \
    s1 += __shfl_xor(s1, 8, 64);                                           \
    float mu = s1 * (1.f / 64.f);                                          \
    float4 dd;                                                             \
    dd.x = A.x - mu; dd.y = A.y - mu; dd.z = A.z - mu; dd.w = A.w - mu;    \
    float s2 = (dd.x * dd.x + dd.y * dd.y) + (dd.z * dd.z + dd.w * dd.w);  \
    s2 += __shfl_xor(s2, 1, 64);                                           \
    s2 += __shfl_xor(s2, 2, 64);                                           \
    s2 += __shfl_xor(s2, 4, 64);                                           \
    s2 += __shfl_xor(s2, 8, 64);                                           \
    float rstd = rsqrtf(s2 * (1.f / 64.f) + 1e-5f);                        \
    long off = (CBASE) + (long)(row0 + m) * C + c0v;                       \
    float4 g4 = *(const float4*)(g + off);                                 \
    ushort4 ob;                                                            \
    ob.x = f2bf((dd.x * rstd * lw4.x + lb4.x) * g4.x);                     \
    ob.y = f2bf((dd.y * rstd * lw4.y + lb4.y) * g4.y);                     \
    ob.z = f2bf((dd.z * rstd * lw4.z + lb4.z) * g4.z);                     \
    ob.w = f2bf((dd.w * rstd * lw4.w + lb4.w) * g4.w);                     \
    *(ushort4*)(z + off) = ob;                                             \
  }

  // ================= chunk A =================
  PHASE1(pd0)
  __syncthreads();                                           // b3 (V(A),Rt(B) in)
  {
    float4 acc0 = {0.f, 0.f, 0.f, 0.f};
    float4 acc1 = {0.f, 0.f, 0.f, 0.f};
    float4 acc2 = {0.f, 0.f, 0.f, 0.f};
    float4 acc3 = {0.f, 0.f, 0.f, 0.f};
    PASSA
    __syncthreads();                                         // b4 (TA,TB dead)
    // async Kt(B)->TB (lands by b5)
#pragma unroll
    for (int i = 0; i < 4; i++) {
      int chunk = wid * 4 + i;
      int row = chunk * 4 + (lane >> 4);
      int cq = lane & 15;
      GLDS16(kt + cbase1 + (long)row * C + cq * 4, TB + chunk * 256);
    }
    WRQ_ALL                                                  // Rt^T(A)->TA
    __syncthreads();                                         // b5
    PASSB(scp0)
    GNROW(acc0, 0, cbase0)
    GNROW(acc1, 1, cbase0)
    GNROW(acc2, 2, cbase0)
    GNROW(acc3, 3, cbase0)
  }
  // rreg <- chunk B's Rt (TC resident since b3, read-only)
#pragma unroll
  for (int q = 0; q < 16; q++)
    rreg[q] = *(const float4*)(TC + tau * 64 + ((q ^ (tau & 15)) * 4));
  __syncthreads();                                           // b6 (TA free)

  // ================= chunk B =================
  // async V(B)->TA (lands during phase1)
#pragma unroll
  for (int i = 0; i < 4; i++) {
    int chunk = wid * 4 + i;
    int row = chunk * 4 + (lane >> 4);
    GLDS16(v + cbase1 + (long)row * C + (lane & 15) * 4, TA + chunk * 256);
  }
  PHASE1(pd1)
  __syncthreads();                                           // b7
  {
    float4 acc0 = {0.f, 0.f, 0.f, 0.f};
    float4 acc1 = {0.f, 0.f, 0.f, 0.f};
    float4 acc2 = {0.f, 0.f, 0.f, 0.f};
    float4 acc3 = {0.f, 0.f, 0.f, 0.f};
    PASSA
    __syncthreads();                                         // b8
    WRQ_ALL                                                  // Rt^T(B)->TA
    __syncthreads();                                         // b9
    PASSB(scp1)
    GNROW(acc0, 0, cbase1)
    GNROW(acc1, 1, cbase1)
    GNROW(acc2, 2, cbase1)
    GNROW(acc3, 3, cbase1)
  }
#undef PHASE1
#undef FMA1
#undef PASSA
#undef PASSB
#undef WRQ
#undef WRQ_ALL
#undef GNROW
}

// ---------------------------------------------------------------- launch ---
extern "C" void kernel_launch(void* const* d_in, const int* in_sizes, int n_in,
                              void* d_out, int out_size, void* d_ws, size_t ws_size,
                              hipStream_t stream) {
  const int B = 8, T = 1024, C = 768, H = 12, ph = 32, pw = 32;
  const int M = B * T;
  const int L = 64, NCH = T / L;

  const float* x        = (const float*)d_in[0];
  const float* W_r      = (const float*)d_in[1];
  const float* W_k      = (const float*)d_in[2];
  const float* W_v      = (const float*)d_in[3];
  const float* W_g      = (const float*)d_in[4];
  const float* W_o      = (const float*)d_in[5];
  const float* maa_x    = (const float*)d_in[6];
  const float* maa_w    = (const float*)d_in[7];
  const float* maa_k    = (const float*)d_in[8];
  const float* maa_v    = (const float*)d_in[9];
  const float* maa_r    = (const float*)d_in[10];
  const float* maa_g    = (const float*)d_in[11];
  const float* maa_w1   = (const float*)d_in[12];
  const float* maa_w2   = (const float*)d_in[13];
  const float* time_dec = (const float*)d_in[14];
  const float* dec_w1   = (const float*)d_in[15];
  const float* dec_w2   = (const float*)d_in[16];
  const float* faaaa    = (const float*)d_in[17];
  const float* ln_w     = (const float*)d_in[18];
  const float* ln_b     = (const float*)d_in[19];

  float* ws = (float*)d_ws;
  const size_t S = (size_t)M * C;
  float* F0 = ws + 0 * S;   // r -> kvb
  float* F1 = ws + 1 * S;   // xxx_bf -> k -> Scb
  float* F2 = ws + 2 * S;   // xw_bf -> w -> Kt (in place)
  float* F3 = ws + 3 * S;   // v
  float* F4 = ws + 4 * S;   // g
  float* F5 = ws + 5 * S;   // xr_bf | xk_bf -> Rt (fp32)
  float* F6 = ws + 6 * S;   // xv_bf | xg_bf -> z_bf
  float* t5    = ws + 7 * S;            // [M,160] bf16 t5b -> bf16 W_r..W_g
  float* t6    = t5 + (size_t)M * 160;  // bf16 W_o + maa1T + decT
  float* aLb   = t6 + (size_t)M * 64;
  float* pdiag = aLb + (size_t)B * H * NCH * 64;
  float* dec_t = pdiag + (size_t)B * H * T;   // [M,64] t_bf + w2T scratch

  ushort* xxx_bf = (ushort*)F1;
  ushort* xw_bf = (ushort*)F2;
  ushort* xr_bf = (ushort*)F5;
  ushort* xk_bf = xr_bf + S;
  ushort* xv_bf = (ushort*)F6;
  ushort* xg_bf = xv_bf + S;
  ushort* z_bf  = (ushort*)F6;
  ushort* t5b   = (ushort*)t5;          // [M,160] bf16
  ushort* t_bf  = (ushort*)dec_t;       // [M,64] bf16
  ushort* w2T   = t_bf + (size_t)M * 64;  // [768,160] bf16 (dead after mix5)
  float* kvb = F0;
  float* Scb = F1;
  const int WSZ = C * C;
  ushort* wr_bf = (ushort*)t5;
  ushort* wk_bf = wr_bf + WSZ;
  ushort* wv_bf = wk_bf + WSZ;
  ushort* wg_bf = wv_bf + WSZ;
  ushort* wo_bf = (ushort*)t6;
  ushort* maa1T = wo_bf + WSZ;          // [256,768]
  ushort* w1dT  = maa1T + 256 * 768;    // [128,768]
  ushort* w2dT  = w1dT + 128 * 768;    // [768,64]

  // 1. qshift (xxx bf16 only; xx recomputed in mix5m)
  {
    long total = (long)M * C;
    k_qshift<<<(int)((total + 255) / 256), 256, 0, stream>>>(
        x, maa_x, xxx_bf, B, T, C, ph, pw);
  }
  // 2. fused weight transposes -> bf16; t5b = tanh(xxx @ maa_w1) via MFMA
  {
    k_wprep<<<1824, 256, 0, stream>>>(maa_w1, maa_w2, dec_w1, dec_w2,
                                      maa1T, w2T, w1dT, w2dT);
    dim3 grid(2, M / 128);
    k_gemm_bf<EPI_TANH, true, true><<<grid, 256, 0, stream>>>(
        xxx_bf, maa1T, nullptr, t5b, M, 160, C);
  }
  // 3. mix5 on MFMA (all outputs bf16; dh inline)
  {
    dim3 grid(C / 128, M / 64);
    k_mix5m<<<grid, 256, 0, stream>>>(t5b, w2T, x, maa_w, maa_k, maa_v,
                                      maa_r, maa_g, xw_bf, xk_bf, xv_bf, xr_bf,
                                      xg_bf, C, T, ph, pw);
  }
  // 4. weight conversion (t5b data dead now)
  {
    dim3 grid((WSZ / 4 + 255) / 256, 5);
    k_cvt5<<<grid, 256, 0, stream>>>(W_r, W_k, W_v, W_g, W_o,
                                     wr_bf, wk_bf, wv_bf, wg_bf, wo_bf, WSZ);
  }
  // 5. big projections: ONE batched bf16 MFMA dispatch (1536 blocks, 1D)
  {
    k_proj4<<<(C / 128) * (M / 128) * 4, 256, 0, stream>>>(
        xr_bf, xk_bf, xv_bf, xg_bf, wr_bf, wk_bf, wv_bf, wg_bf,
        F0, F1, F3, F4, M, C, C);
  }
  // 6. decay path on MFMA
  {
    dim3 g1(1, M / 128);
    k_gemm_bf<EPI_TANH, true, true><<<g1, 256, 0, stream>>>(
        xw_bf, w1dT, nullptr, t_bf, M, 64, C);
    dim3 g2(C / 128, M / 128);
    k_gemm_bf<EPI_BIAS, false, false><<<g2, 256, 0, stream>>>(
        t_bf, w2dT, time_dec, F2, M, C, 64);
  }
  // 7. chunked wkv6: pre -> kv -> scan -> intra(+GN+gate -> z bf16)
  k_wkv_pre<<<B * H * NCH, 64, 0, stream>>>(F0, F1, F2, faaaa, F5, F2,
                                            aLb, pdiag, B, T, C, H, L);
  k_wkv_kv<<<B * H * NCH, 256, 0, stream>>>(F2, F3, kvb, B, T, C, H, L);
  k_wkv_scan<<<B * H * 16, 256, 0, stream>>>(kvb, aLb, Scb, NCH);
  k_wkv_intra<<<B * H * (NCH / 2), 256, 0, stream>>>(
      F5, F2, F3, pdiag, Scb, F4, ln_w, ln_b, z_bf, B, T, C, H, L);
  // 8. out = z @ W_o^T (bf16 MFMA)
  {
    dim3 grid(C / 128, M / 128);
    k_gemm_bf<EPI_NONE, false, false><<<grid, 256, 0, stream>>>(
        z_bf, wo_bf, nullptr, (float*)d_out, M, C, C);
  }
}

// Round 7
// 385.822 us; speedup vs baseline: 1.0929x; 1.0929x over previous
//
#include <hip/hip_runtime.h>
#include <math.h>

// ---------------------------------------------------------------------------
// TimeMix (RWKV-6 vision block) — round 16: k_wkv_intra phase-1 re-decomposed
// as register outer-product over transposed-staged KtT/RtT [chan][time].
// 2 b128 -> 16 FMA (was 1 b128 -> 4 FMA broadcast); rreg/WRQ deleted; passB
// reads RtT directly; V,S direct from L2; 2 barriers/chunk (was ~5).
// LDS 3x[64][68] fp32 = 51KB -> 3 blocks/CU. B=8, T=1024, C=768, H=12.
// ---------------------------------------------------------------------------

#define EPI_NONE 0
#define EPI_TANH 1
#define EPI_RELU 2
#define EPI_BIAS 3

typedef float f32x4 __attribute__((ext_vector_type(4)));
typedef __bf16 bf16x8 __attribute__((ext_vector_type(8)));

__device__ __forceinline__ ushort f2bf(float x) {
  unsigned u = __float_as_uint(x);
  return (ushort)((u + 0x7fffu + ((u >> 16) & 1u)) >> 16);
}

#define GLDS16(gp, lp)                                                   \
  __builtin_amdgcn_global_load_lds(                                      \
      (const __attribute__((address_space(1))) void*)(gp),               \
      (__attribute__((address_space(3))) void*)(lp), 16, 0, 0)

// ---------------------------------------------------------------- qshift ---
__global__ __launch_bounds__(256) void k_qshift(
    const float* __restrict__ x, const float* __restrict__ maa_x,
    ushort* __restrict__ xxx_bf,
    int B, int T, int C, int ph, int pw) {
  long idx = (long)blockIdx.x * blockDim.x + threadIdx.x;
  long total = (long)B * T * C;
  if (idx >= total) return;
  int c = (int)(idx % C);
  long bt = idx / C;
  int t = (int)(bt % T);
  int quarter = (c & 63) >> 4;
  int hh = t / pw;
  int ww = t - hh * pw;
  long rowbase = (bt - t) * C;
  float sval = 0.f;
  int st = -1;
  if (quarter == 0)      { if (ww >= 1)      st = t - 1;  }
  else if (quarter == 1) { if (ww < pw - 1)  st = t + 1;  }
  else if (quarter == 2) { if (hh >= 1)      st = t - pw; }
  else                   { if (hh < ph - 1)  st = t + pw; }
  if (st >= 0) sval = x[rowbase + (long)st * C + c];
  float xval = x[idx];
  float d = sval - xval;
  xxx_bf[idx] = f2bf(xval + d * maa_x[c]);
}

// ----------------- fused weight transposes -> bf16 (one launch) ------------
__global__ __launch_bounds__(256) void k_wprep(
    const float* __restrict__ w1, const float* __restrict__ w2,
    const float* __restrict__ dw1, const float* __restrict__ dw2,
    ushort* __restrict__ maa1T, ushort* __restrict__ w2T,
    ushort* __restrict__ w1dT, ushort* __restrict__ w2dT) {
  int idx = blockIdx.x * 256 + threadIdx.x;
  if (idx < 196608) {
    int n = idx / 768, k = idx - n * 768;
    maa1T[idx] = f2bf(n < 160 ? w1[(size_t)k * 160 + n] : 0.f);
  } else if (idx < 196608 + 122880) {
    int j = idx - 196608;
    int c = j / 160, kk = j - c * 160;
    w2T[j] = f2bf(w2[(size_t)kk * 768 + c]);
  } else if (idx < 196608 + 122880 + 98304) {
    int j = idx - (196608 + 122880);
    int n = j / 768, k = j - n * 768;
    w1dT[j] = f2bf(n < 64 ? dw1[(size_t)k * 64 + n] : 0.f);
  } else {
    int j = idx - (196608 + 122880 + 98304);
    int n = j >> 6, k = j & 63;
    w2dT[j] = f2bf(dw2[(size_t)k * 768 + n]);
  }
}

// --------------------------- mix5 on MFMA, no LDS, no barriers -------------
__global__ __launch_bounds__(256) void k_mix5m(
    const ushort* __restrict__ t5b, const ushort* __restrict__ w2T,
    const float* __restrict__ x,
    const float* __restrict__ maa_w, const float* __restrict__ maa_k,
    const float* __restrict__ maa_v, const float* __restrict__ maa_r,
    const float* __restrict__ maa_g,
    ushort* __restrict__ xw, ushort* __restrict__ xk, ushort* __restrict__ xvb,
    ushort* __restrict__ xr, ushort* __restrict__ xg,
    int C, int T, int ph, int pw) {
  int tid = threadIdx.x;
  int lane = tid & 63, wid = tid >> 6;
  int m0 = blockIdx.y * 64, n0 = blockIdx.x * 128;
  int lm = lane & 15, lk = (lane >> 4) * 8;
  int rq = (lane >> 4) * 4;
  const ushort* ap = t5b + (size_t)(m0 + wid * 16 + lm) * 160 + lk;

  int stq[4][4];
#pragma unroll
  for (int q = 0; q < 4; q++) {
    int mr = m0 + wid * 16 + rq + q;
    int t = mr % T;
    int hh = t / pw, ww = t - hh * pw;
    stq[q][0] = (ww >= 1)      ? mr - 1  : -1;
    stq[q][1] = (ww < pw - 1)  ? mr + 1  : -1;
    stq[q][2] = (hh >= 1)      ? mr - pw : -1;
    stq[q][3] = (hh < ph - 1)  ? mr + pw : -1;
  }

  float xh[8][4], dh[8][4];
#pragma unroll
  for (int j = 0; j < 8; j++)
#pragma unroll
    for (int q = 0; q < 4; q++) {
      int mr = m0 + wid * 16 + rq + q;
      int col = n0 + j * 16 + lm;
      float xv = x[(size_t)mr * C + col];
      int sr = stq[q][j & 3];
      float sv = (sr >= 0) ? x[(size_t)sr * C + col] : 0.f;
      xh[j][q] = xv;
      dh[j][q] = sv - xv;
    }

#pragma unroll
  for (int f = 0; f < 5; f++) {
    bf16x8 af = *(const bf16x8*)(ap + f * 32);
    f32x4 acc[8];
#pragma unroll
    for (int j = 0; j < 8; j++) {
      bf16x8 bfj = *(const bf16x8*)(w2T +
          (size_t)(n0 + j * 16 + lm) * 160 + f * 32 + lk);
      acc[j] = __builtin_amdgcn_mfma_f32_16x16x32_bf16(
          af, bfj, (f32x4){0.f, 0.f, 0.f, 0.f}, 0, 0, 0);
    }
    const float* maa_f = (f == 0) ? maa_w : (f == 1) ? maa_k
                        : (f == 2) ? maa_v : (f == 3) ? maa_r : maa_g;
    ushort* dst = (f == 0) ? xw : (f == 1) ? xk
                 : (f == 2) ? xvb : (f == 3) ? xr : xg;
#pragma unroll
    for (int j = 0; j < 8; j++) {
      float mf = maa_f[n0 + j * 16 + lm];
#pragma unroll
      for (int q = 0; q < 4; q++) {
        size_t off = (size_t)(m0 + wid * 16 + rq + q) * C + (n0 + j * 16 + lm);
        dst[off] = f2bf(xh[j][q] + dh[j][q] * (mf + acc[j][q]));
      }
    }
  }
}

// -------------------------------------------- fp32 -> bf16 cvt (5 arrays) --
__global__ __launch_bounds__(256) void k_cvt5(
    const float* __restrict__ s0, const float* __restrict__ s1,
    const float* __restrict__ s2, const float* __restrict__ s3,
    const float* __restrict__ s4,
    ushort* __restrict__ d0, ushort* __restrict__ d1,
    ushort* __restrict__ d2, ushort* __restrict__ d3,
    ushort* __restrict__ d4, int n) {
  const float* s;
  ushort* d;
  switch (blockIdx.y) {
    case 0: s = s0; d = d0; break;
    case 1: s = s1; d = d1; break;
    case 2: s = s2; d = d2; break;
    case 3: s = s3; d = d3; break;
    default: s = s4; d = d4; break;
  }
  int i = (blockIdx.x * 256 + threadIdx.x) * 4;
  if (i >= n) return;
  float4 v = *(const float4*)(s + i);
  ushort4 o;
  o.x = f2bf(v.x); o.y = f2bf(v.y); o.z = f2bf(v.z); o.w = f2bf(v.w);
  *(ushort4*)(d + i) = o;
}

// ----------------------------------------------------- bf16 MFMA GEMM ------
template <int EPI, bool NMASK, bool OBF16>
__global__ __launch_bounds__(256) void k_gemm_bf(
    const ushort* __restrict__ A, const ushort* __restrict__ W,
    const float* __restrict__ bias, void* __restrict__ Cm,
    int M, int N, int K) {
  __shared__ ushort Al[128 * 64];
  __shared__ ushort Bl[128 * 64];
  int nwg = gridDim.x * gridDim.y;
  int bid = blockIdx.y * gridDim.x + blockIdx.x;
  int swz = (nwg & 7) == 0 ? ((bid & 7) * (nwg >> 3) + (bid >> 3)) : bid;
  int bx = swz % gridDim.x, by = swz / gridDim.x;
  int m0 = by * 128, n0 = bx * 128;
  int tid = threadIdx.x;
  int lane = tid & 63, wave = tid >> 6;
  int wm = (wave >> 1) * 64, wn = (wave & 1) * 64;
  int lm = lane & 15, g = lane >> 4;
  f32x4 acc[4][4];
#pragma unroll
  for (int i = 0; i < 4; i++)
#pragma unroll
    for (int j = 0; j < 4; j++) acc[i][j] = (f32x4){0.f, 0.f, 0.f, 0.f};

  for (int k0 = 0; k0 < K; k0 += 64) {
#pragma unroll
    for (int i = 0; i < 4; i++) {
      int cid = tid + i * 256;             // 0..1023 16B-chunks
      int row = cid >> 3, p = cid & 7;
      int cq = p ^ (row & 7);
      GLDS16(A + (size_t)(m0 + row) * K + k0 + cq * 8, Al + cid * 8);
      GLDS16(W + (size_t)(n0 + row) * K + k0 + cq * 8, Bl + cid * 8);
    }
    __syncthreads();
#pragma unroll
    for (int s = 0; s < 2; s++) {
      bf16x8 af[4], bf[4];
#pragma unroll
      for (int i = 0; i < 4; i++) {
        int r = wm + i * 16 + lm;
        af[i] = *(const bf16x8*)&Al[r * 64 + (((s * 4 + g) ^ (r & 7)) * 8)];
        int rb = wn + i * 16 + lm;
        bf[i] = *(const bf16x8*)&Bl[rb * 64 + (((s * 4 + g) ^ (rb & 7)) * 8)];
      }
#pragma unroll
      for (int i = 0; i < 4; i++)
#pragma unroll
        for (int j = 0; j < 4; j++)
          acc[i][j] = __builtin_amdgcn_mfma_f32_16x16x32_bf16(
              af[i], bf[j], acc[i][j], 0, 0, 0);
    }
    __syncthreads();
  }
  int rq = (lane >> 4) * 4;
#pragma unroll
  for (int i = 0; i < 4; i++) {
#pragma unroll
    for (int j = 0; j < 4; j++) {
      int gn = n0 + wn + j * 16 + lm;
      if (NMASK && gn >= N) continue;
      float bv = (EPI == EPI_BIAS) ? bias[gn] : 0.f;
#pragma unroll
      for (int q = 0; q < 4; q++) {
        int gm = m0 + wm + i * 16 + rq + q;
        float val = acc[i][j][q];
        if (EPI == EPI_BIAS) val += bv;
        if (EPI == EPI_RELU) val = fmaxf(val, 0.f);
        if (EPI == EPI_TANH) val = tanhf(val);
        if (OBF16) ((ushort*)Cm)[(size_t)gm * N + gn] = f2bf(val);
        else       ((float*)Cm)[(size_t)gm * N + gn] = val;
      }
    }
  }
}

// --------------------------------- batched 4-projection bf16 MFMA GEMM -----
__global__ __launch_bounds__(256) void k_proj4(
    const ushort* __restrict__ A0, const ushort* __restrict__ A1,
    const ushort* __restrict__ A2, const ushort* __restrict__ A3,
    const ushort* __restrict__ W0, const ushort* __restrict__ W1,
    const ushort* __restrict__ W2, const ushort* __restrict__ W3,
    float* __restrict__ C0, float* __restrict__ C1,
    float* __restrict__ C2, float* __restrict__ C3,
    int M, int N, int K) {
  int nwg = gridDim.x;                       // 1536, %8==0
  int bid = blockIdx.x;
  int swz = (bid & 7) * (nwg >> 3) + (bid >> 3);
  int nxt = N / 128;                         // 6
  int per_z = (M / 128) * nxt;               // 384
  int z = swz / per_z;
  int rem = swz - z * per_z;
  int my = rem / nxt, nx = rem - my * nxt;
  const ushort* A = (z == 0) ? A0 : (z == 1) ? A1 : (z == 2) ? A2 : A3;
  const ushort* W = (z == 0) ? W0 : (z == 1) ? W1 : (z == 2) ? W2 : W3;
  float* Cm       = (z == 0) ? C0 : (z == 1) ? C1 : (z == 2) ? C2 : C3;
  __shared__ ushort Al[128 * 64];
  __shared__ ushort Bl[128 * 64];
  int tid = threadIdx.x;
  int m0 = my * 128, n0 = nx * 128;
  int lane = tid & 63, wave = tid >> 6;
  int wm = (wave >> 1) * 64, wn = (wave & 1) * 64;
  int lm = lane & 15, g = lane >> 4;
  f32x4 acc[4][4];
#pragma unroll
  for (int i = 0; i < 4; i++)
#pragma unroll
    for (int j = 0; j < 4; j++) acc[i][j] = (f32x4){0.f, 0.f, 0.f, 0.f};

  for (int k0 = 0; k0 < K; k0 += 64) {
#pragma unroll
    for (int i = 0; i < 4; i++) {
      int cid = tid + i * 256;
      int row = cid >> 3, p = cid & 7;
      int cq = p ^ (row & 7);
      GLDS16(A + (size_t)(m0 + row) * K + k0 + cq * 8, Al + cid * 8);
      GLDS16(W + (size_t)(n0 + row) * K + k0 + cq * 8, Bl + cid * 8);
    }
    __syncthreads();
#pragma unroll
    for (int s = 0; s < 2; s++) {
      bf16x8 af[4], bf[4];
#pragma unroll
      for (int i = 0; i < 4; i++) {
        int r = wm + i * 16 + lm;
        af[i] = *(const bf16x8*)&Al[r * 64 + (((s * 4 + g) ^ (r & 7)) * 8)];
        int rb = wn + i * 16 + lm;
        bf[i] = *(const bf16x8*)&Bl[rb * 64 + (((s * 4 + g) ^ (rb & 7)) * 8)];
      }
#pragma unroll
      for (int i = 0; i < 4; i++)
#pragma unroll
        for (int j = 0; j < 4; j++)
          acc[i][j] = __builtin_amdgcn_mfma_f32_16x16x32_bf16(
              af[i], bf[j], acc[i][j], 0, 0, 0);
    }
    __syncthreads();
  }
  bool relu = (z == 3);
  int rq = (lane >> 4) * 4;
#pragma unroll
  for (int i = 0; i < 4; i++) {
#pragma unroll
    for (int j = 0; j < 4; j++) {
      int gn = n0 + wn + j * 16 + lm;
#pragma unroll
      for (int q = 0; q < 4; q++) {
        int gm = m0 + wm + i * 16 + rq + q;
        float val = acc[i][j][q];
        if (relu) val = fmaxf(val, 0.f);
        Cm[(size_t)gm * N + gn] = val;
      }
    }
  }
}

// ------------------------------------------------- chunked WKV: phase pre --
__global__ __launch_bounds__(64) void k_wkv_pre(
    const float* __restrict__ r, const float* __restrict__ k,
    const float* __restrict__ w, const float* __restrict__ u,
    float* __restrict__ rt, float* __restrict__ kt,
    float* __restrict__ aL, float* __restrict__ pdiag,
    int B, int T, int C, int H, int L) {
  __shared__ float pls[64 * 65];
  int nch = T / L;
  int blk = blockIdx.x;
  int bh = blk / nch, c = blk - bh * nch;
  int b = bh / H, h = bh - b * H;
  int j = threadIdx.x;
  float uj = u[h * 64 + j];
  float cum = 0.f;
  long base = ((long)b * T + (long)c * L) * C + h * 64 + j;
  for (int tau = 0; tau < L; tau++) {
    long off = base + (long)tau * C;
    float wv = w[off];
    float rv = r[off];
    float kv = k[off];
    float e = expf(wv);
    rt[off] = rv * expf(-cum);
    cum += e;
    kt[off] = kv * expf(cum);
    pls[tau * 65 + j] = rv * uj * kv;
  }
  aL[((long)bh * nch + c) * 64 + j] = expf(-cum);
  __syncthreads();
  float s0 = 0.f, s1 = 0.f, s2 = 0.f, s3 = 0.f;
#pragma unroll
  for (int q = 0; q < 16; q++) {
    float4 p4 = *(const float4*)(pls + j * 65 + q * 4);
    s0 += p4.x; s1 += p4.y; s2 += p4.z; s3 += p4.w;
  }
  pdiag[(long)bh * T + c * L + j] = (s0 + s1) + (s2 + s3);
}

// --------------------------------------- chunked WKV: per-chunk KV outer ---
__global__ __launch_bounds__(256) void k_wkv_kv(
    const float* __restrict__ kt, const float* __restrict__ v,
    float* __restrict__ kvb, int B, int T, int C, int H, int L) {
  int nch = T / L;
  int blk = blockIdx.x;
  int bh = blk / nch, c = blk - bh * nch;
  int b = bh / H, h = bh - b * H;
  __shared__ float Ks[64 * 64];
  __shared__ float Vs[64 * 64];
  int tid = threadIdx.x;
  int lane = tid & 63, jg = tid >> 6;
  long cbase = ((long)b * T + (long)c * L) * C + h * 64;
#pragma unroll
  for (int i = 0; i < 4; i++) {
    int chunk = jg * 4 + i;
    int row = chunk * 4 + (lane >> 4);
    int cq = lane & 15;
    GLDS16(kt + cbase + (long)row * C + cq * 4, Ks + chunk * 256);
    GLDS16(v + cbase + (long)row * C + cq * 4, Vs + chunk * 256);
  }
  __syncthreads();
  float acc[16];
#pragma unroll
  for (int q = 0; q < 16; q++) acc[q] = 0.f;
  for (int s = 0; s < 64; s++) {
    float vi = Vs[s * 64 + lane];
#pragma unroll
    for (int q4 = 0; q4 < 4; q4++) {
      float4 kk = *(const float4*)(Ks + s * 64 + jg * 16 + q4 * 4);
      acc[q4 * 4 + 0] = fmaf(kk.x, vi, acc[q4 * 4 + 0]);
      acc[q4 * 4 + 1] = fmaf(kk.y, vi, acc[q4 * 4 + 1]);
      acc[q4 * 4 + 2] = fmaf(kk.z, vi, acc[q4 * 4 + 2]);
      acc[q4 * 4 + 3] = fmaf(kk.w, vi, acc[q4 * 4 + 3]);
    }
  }
  float* out = kvb + ((long)bh * nch + c) * 4096;
#pragma unroll
  for (int q = 0; q < 16; q++) out[(jg * 16 + q) * 64 + lane] = acc[q];
}

// ---------------------------------------- chunked WKV: state prefix scan ---
__global__ __launch_bounds__(256) void k_wkv_scan(
    const float* __restrict__ kvb, const float* __restrict__ aL,
    float* __restrict__ Scb, int nch) {
  int bh = blockIdx.x >> 4;
  int e = ((blockIdx.x & 15) << 8) + threadIdx.x;   // 0..4095
  float S = 0.f;
  for (int c = 0; c < nch; c++) {
    long cb = ((long)bh * nch + c) * 4096 + e;
    Scb[cb] = S;
    S = aL[((long)bh * nch + c) * 64 + (e >> 6)] * (S + kvb[cb]);
  }
}

// ------------- chunked WKV: intra + inter + groupnorm*gate (fused) ---------
// Phase1 as register outer-product: thread (sg,tg) computes P^T[4s x 4tau]
// from KtT/RtT [chan][time] (2 b128 -> 16 FMA). RtT doubles as passB operand
// (rreg/WRQ deleted). V,S read direct from L2 in the fused pass. 2 barriers.
__global__ __launch_bounds__(256, 3) void k_wkv_intra(
    const float* __restrict__ rt, const float* __restrict__ kt,
    const float* __restrict__ v, const float* __restrict__ pdiag,
    const float* __restrict__ Scb, const float* __restrict__ g,
    const float* __restrict__ ln_w, const float* __restrict__ ln_b,
    ushort* __restrict__ z, int B, int T, int C, int H, int L) {
  int nch = T / L;
  int blk = blockIdx.x;
  int bh = blk / nch, c = blk - bh * nch;
  int b = bh / H, h = bh - b * H;
  __shared__ float KtT[64 * 68];   // [chan][time]
  __shared__ float RtT[64 * 68];   // [chan][time] (also passB operand)
  __shared__ float Pt[64 * 68];    // P^T [s][tau]
  int tid = threadIdx.x;
  int lane = tid & 63, wid = tid >> 6;
  long cbase = ((long)b * T + (long)c * L) * C + h * 64;
  const float* scp = Scb + ((long)bh * nch + c) * 4096;

  // --- stage: reg-transpose Kt,Rt -> KtT,RtT ---
  {
    int t0 = (tid >> 4) * 4;        // time group
    int c0s = (tid & 15) * 4;       // chan group
    float4 ka[4], ra[4];
#pragma unroll
    for (int i = 0; i < 4; i++) {
      ka[i] = *(const float4*)(kt + cbase + (long)(t0 + i) * C + c0s);
      ra[i] = *(const float4*)(rt + cbase + (long)(t0 + i) * C + c0s);
    }
#pragma unroll
    for (int j = 0; j < 4; j++) {
      float4 ko, ro;
      ko.x = ka[0][j]; ko.y = ka[1][j]; ko.z = ka[2][j]; ko.w = ka[3][j];
      ro.x = ra[0][j]; ro.y = ra[1][j]; ro.z = ra[2][j]; ro.w = ra[3][j];
      *(float4*)(KtT + (c0s + j) * 68 + t0) = ko;
      *(float4*)(RtT + (c0s + j) * 68 + t0) = ro;
    }
  }
  __syncthreads();                                           // b1

  // --- phase 1: outer-product P^T[s0..3][tau0..3] ---
  {
    int s0 = (tid >> 4) * 4;
    int tau0 = (tid & 15) * 4;
    float4 pd4 = *(const float4*)(pdiag + (long)bh * T + c * L + tau0);
    float p00 = 0.f, p01 = 0.f, p02 = 0.f, p03 = 0.f;
    float p10 = 0.f, p11 = 0.f, p12 = 0.f, p13 = 0.f;
    float p20 = 0.f, p21 = 0.f, p22 = 0.f, p23 = 0.f;
    float p30 = 0.f, p31 = 0.f, p32 = 0.f, p33 = 0.f;
#pragma unroll 4
    for (int cc = 0; cc < 64; cc++) {
      float4 kq = *(const float4*)(KtT + cc * 68 + s0);
      float4 rq = *(const float4*)(RtT + cc * 68 + tau0);
      p00 = fmaf(kq.x, rq.x, p00); p01 = fmaf(kq.x, rq.y, p01);
      p02 = fmaf(kq.x, rq.z, p02); p03 = fmaf(kq.x, rq.w, p03);
      p10 = fmaf(kq.y, rq.x, p10); p11 = fmaf(kq.y, rq.y, p11);
      p12 = fmaf(kq.y, rq.z, p12); p13 = fmaf(kq.y, rq.w, p13);
      p20 = fmaf(kq.z, rq.x, p20); p21 = fmaf(kq.z, rq.y, p21);
      p22 = fmaf(kq.z, rq.z, p22); p23 = fmaf(kq.z, rq.w, p23);
      p30 = fmaf(kq.w, rq.x, p30); p31 = fmaf(kq.w, rq.y, p31);
      p32 = fmaf(kq.w, rq.z, p32); p33 = fmaf(kq.w, rq.w, p33);
    }
#define PMASK(PI0, PI1, PI2, PI3, I)                                       \
    {                                                                      \
      int s = s0 + (I);                                                    \
      float4 o;                                                            \
      o.x = (s < tau0 + 0) ? PI0 : (s == tau0 + 0 ? pd4.x : 0.f);          \
      o.y = (s < tau0 + 1) ? PI1 : (s == tau0 + 1 ? pd4.y : 0.f);          \
      o.z = (s < tau0 + 2) ? PI2 : (s == tau0 + 2 ? pd4.z : 0.f);          \
      o.w = (s < tau0 + 3) ? PI3 : (s == tau0 + 3 ? pd4.w : 0.f);          \
      *(float4*)(Pt + s * 68 + tau0) = o;                                  \
    }
    PMASK(p00, p01, p02, p03, 0)
    PMASK(p10, p11, p12, p13, 1)
    PMASK(p20, p21, p22, p23, 2)
    PMASK(p30, p31, p32, p33, 3)
#undef PMASK
  }
  __syncthreads();                                           // b2

  // --- fused pass: Y = P^T(row0..3) . V  +  RtT(row0..3) . S ---
  int row0 = wid * 16 + ((lane >> 4) << 2);   // 4 output taus
  int c0v = (lane & 15) * 4;                  // 4 output chans
  float4 acc0 = {0.f, 0.f, 0.f, 0.f};
  float4 acc1 = {0.f, 0.f, 0.f, 0.f};
  float4 acc2 = {0.f, 0.f, 0.f, 0.f};
  float4 acc3 = {0.f, 0.f, 0.f, 0.f};
  const float* vp = v + cbase + c0v;
#define FMA2(A, P, V4, R, S4)                          \
  A.x = fmaf(P, V4.x, fmaf(R, S4.x, A.x));             \
  A.y = fmaf(P, V4.y, fmaf(R, S4.y, A.y));             \
  A.z = fmaf(P, V4.z, fmaf(R, S4.z, A.z));             \
  A.w = fmaf(P, V4.w, fmaf(R, S4.w, A.w));
#pragma unroll 4
  for (int j = 0; j < 64; j++) {
    float4 pp = *(const float4*)(Pt + j * 68 + row0);    // 16-lane multicast
    float4 rr = *(const float4*)(RtT + j * 68 + row0);   // 16-lane multicast
    float4 vv = *(const float4*)(vp + (long)j * C);      // L2, 256B/wave
    float4 ssv = *(const float4*)(scp + j * 64 + c0v);   // L2, 256B/wave
    FMA2(acc0, pp.x, vv, rr.x, ssv);
    FMA2(acc1, pp.y, vv, rr.y, ssv);
    FMA2(acc2, pp.z, vv, rr.z, ssv);
    FMA2(acc3, pp.w, vv, rr.w, ssv);
  }
#undef FMA2

  // ---- fused groupnorm (per row over this head's 64 channels) * gate ----
  float4 lw4 = *(const float4*)(ln_w + h * 64 + c0v);
  float4 lb4 = *(const float4*)(ln_b + h * 64 + c0v);
#define GNROW(A, m)                                                        \
  {                                                                        \
    float s1 = (A.x + A.y) + (A.z + A.w);                                  \
    s1 += __shfl_xor(s1, 1, 64);                                           \
    s1 += __shfl_xor(s1, 2, 64);                                           \
    s1 += __shfl_xor(s1, 4, 64);                                           \
    s1 += __shfl_xor(s1, 8, 64);                                           \
    float mu = s1 * (1.f / 64.f);                                          \
    float4 dd;                                                             \
    dd.x = A.x - mu; dd.y = A.y - mu; dd.z = A.z - mu; dd.w = A.w - mu;    \
    float s2 = (dd.x * dd.x + dd.y * dd.y) + (dd.z * dd.z + dd.w * dd.w);  \
    s2 += __shfl_xor(s2, 1, 64);                                           \
    s2 += __shfl_xor(s2, 2, 64);                                           \
    s2 += __shfl_xor(s2, 4, 64);                                           \
    s2 += __shfl_xor(s2, 8, 64);                                           \
    float rstd = rsqrtf(s2 * (1.f / 64.f) + 1e-5f);                        \
    long off = cbase + (long)(row0 + m) * C + c0v;                         \
    float4 g4 = *(const float4*)(g + off);                                 \
    ushort4 ob;                                                            \
    ob.x = f2bf((dd.x * rstd * lw4.x + lb4.x) * g4.x);                     \
    ob.y = f2bf((dd.y * rstd * lw4.y + lb4.y) * g4.y);                     \
    ob.z = f2bf((dd.z * rstd * lw4.z + lb4.z) * g4.z);                     \
    ob.w = f2bf((dd.w * rstd * lw4.w + lb4.w) * g4.w);                     \
    *(ushort4*)(z + off) = ob;                                             \
  }
  GNROW(acc0, 0)
  GNROW(acc1, 1)
  GNROW(acc2, 2)
  GNROW(acc3, 3)
#undef GNROW
}

// ---------------------------------------------------------------- launch ---
extern "C" void kernel_launch(void* const* d_in, const int* in_sizes, int n_in,
                              void* d_out, int out_size, void* d_ws, size_t ws_size,
                              hipStream_t stream) {
  const int B = 8, T = 1024, C = 768, H = 12, ph = 32, pw = 32;
  const int M = B * T;
  const int L = 64, NCH = T / L;

  const float* x        = (const float*)d_in[0];
  const float* W_r      = (const float*)d_in[1];
  const float* W_k      = (const float*)d_in[2];
  const float* W_v      = (const float*)d_in[3];
  const float* W_g      = (const float*)d_in[4];
  const float* W_o      = (const float*)d_in[5];
  const float* maa_x    = (const float*)d_in[6];
  const float* maa_w    = (const float*)d_in[7];
  const float* maa_k    = (const float*)d_in[8];
  const float* maa_v    = (const float*)d_in[9];
  const float* maa_r    = (const float*)d_in[10];
  const float* maa_g    = (const float*)d_in[11];
  const float* maa_w1   = (const float*)d_in[12];
  const float* maa_w2   = (const float*)d_in[13];
  const float* time_dec = (const float*)d_in[14];
  const float* dec_w1   = (const float*)d_in[15];
  const float* dec_w2   = (const float*)d_in[16];
  const float* faaaa    = (const float*)d_in[17];
  const float* ln_w     = (const float*)d_in[18];
  const float* ln_b     = (const float*)d_in[19];

  float* ws = (float*)d_ws;
  const size_t S = (size_t)M * C;
  float* F0 = ws + 0 * S;   // r -> kvb
  float* F1 = ws + 1 * S;   // xxx_bf -> k -> Scb
  float* F2 = ws + 2 * S;   // xw_bf -> w -> Kt (in place)
  float* F3 = ws + 3 * S;   // v
  float* F4 = ws + 4 * S;   // g
  float* F5 = ws + 5 * S;   // xr_bf | xk_bf -> Rt (fp32)
  float* F6 = ws + 6 * S;   // xv_bf | xg_bf -> z_bf
  float* t5    = ws + 7 * S;            // [M,160] bf16 t5b -> bf16 W_r..W_g
  float* t6    = t5 + (size_t)M * 160;  // bf16 W_o + maa1T + decT
  float* aLb   = t6 + (size_t)M * 64;
  float* pdiag = aLb + (size_t)B * H * NCH * 64;
  float* dec_t = pdiag + (size_t)B * H * T;   // [M,64] t_bf + w2T scratch

  ushort* xxx_bf = (ushort*)F1;
  ushort* xw_bf = (ushort*)F2;
  ushort* xr_bf = (ushort*)F5;
  ushort* xk_bf = xr_bf + S;
  ushort* xv_bf = (ushort*)F6;
  ushort* xg_bf = xv_bf + S;
  ushort* z_bf  = (ushort*)F6;
  ushort* t5b   = (ushort*)t5;          // [M,160] bf16
  ushort* t_bf  = (ushort*)dec_t;       // [M,64] bf16
  ushort* w2T   = t_bf + (size_t)M * 64;  // [768,160] bf16 (dead after mix5)
  float* kvb = F0;
  float* Scb = F1;
  const int WSZ = C * C;
  ushort* wr_bf = (ushort*)t5;
  ushort* wk_bf = wr_bf + WSZ;
  ushort* wv_bf = wk_bf + WSZ;
  ushort* wg_bf = wv_bf + WSZ;
  ushort* wo_bf = (ushort*)t6;
  ushort* maa1T = wo_bf + WSZ;          // [256,768]
  ushort* w1dT  = maa1T + 256 * 768;    // [128,768]
  ushort* w2dT  = w1dT + 128 * 768;    // [768,64]

  // 1. qshift (xxx bf16 only; xx recomputed in mix5m)
  {
    long total = (long)M * C;
    k_qshift<<<(int)((total + 255) / 256), 256, 0, stream>>>(
        x, maa_x, xxx_bf, B, T, C, ph, pw);
  }
  // 2. fused weight transposes -> bf16; t5b = tanh(xxx @ maa_w1) via MFMA
  {
    k_wprep<<<1824, 256, 0, stream>>>(maa_w1, maa_w2, dec_w1, dec_w2,
                                      maa1T, w2T, w1dT, w2dT);
    dim3 grid(2, M / 128);
    k_gemm_bf<EPI_TANH, true, true><<<grid, 256, 0, stream>>>(
        xxx_bf, maa1T, nullptr, t5b, M, 160, C);
  }
  // 3. mix5 on MFMA (all outputs bf16; dh inline)
  {
    dim3 grid(C / 128, M / 64);
    k_mix5m<<<grid, 256, 0, stream>>>(t5b, w2T, x, maa_w, maa_k, maa_v,
                                      maa_r, maa_g, xw_bf, xk_bf, xv_bf, xr_bf,
                                      xg_bf, C, T, ph, pw);
  }
  // 4. weight conversion (t5b data dead now)
  {
    dim3 grid((WSZ / 4 + 255) / 256, 5);
    k_cvt5<<<grid, 256, 0, stream>>>(W_r, W_k, W_v, W_g, W_o,
                                     wr_bf, wk_bf, wv_bf, wg_bf, wo_bf, WSZ);
  }
  // 5. big projections: ONE batched bf16 MFMA dispatch (1536 blocks, 1D)
  {
    k_proj4<<<(C / 128) * (M / 128) * 4, 256, 0, stream>>>(
        xr_bf, xk_bf, xv_bf, xg_bf, wr_bf, wk_bf, wv_bf, wg_bf,
        F0, F1, F3, F4, M, C, C);
  }
  // 6. decay path on MFMA
  {
    dim3 g1(1, M / 128);
    k_gemm_bf<EPI_TANH, true, true><<<g1, 256, 0, stream>>>(
        xw_bf, w1dT, nullptr, t_bf, M, 64, C);
    dim3 g2(C / 128, M / 128);
    k_gemm_bf<EPI_BIAS, false, false><<<g2, 256, 0, stream>>>(
        t_bf, w2dT, time_dec, F2, M, C, 64);
  }
  // 7. chunked wkv6: pre -> kv -> scan -> intra(+GN+gate -> z bf16)
  k_wkv_pre<<<B * H * NCH, 64, 0, stream>>>(F0, F1, F2, faaaa, F5, F2,
                                            aLb, pdiag, B, T, C, H, L);
  k_wkv_kv<<<B * H * NCH, 256, 0, stream>>>(F2, F3, kvb, B, T, C, H, L);
  k_wkv_scan<<<B * H * 16, 256, 0, stream>>>(kvb, aLb, Scb, NCH);
  k_wkv_intra<<<B * H * NCH, 256, 0, stream>>>(
      F5, F2, F3, pdiag, Scb, F4, ln_w, ln_b, z_bf, B, T, C, H, L);
  // 8. out = z @ W_o^T (bf16 MFMA)
  {
    dim3 grid(C / 128, M / 128);
    k_gemm_bf<EPI_NONE, false, false><<<grid, 256, 0, stream>>>(
        z_bf, wo_bf, nullptr, (float*)d_out, M, C, C);
  }
}

// Round 9
// 383.249 us; speedup vs baseline: 1.1002x; 1.0067x over previous
//
#include <hip/hip_runtime.h>
#include <math.h>

// ---------------------------------------------------------------------------
// TimeMix (RWKV-6 vision block) — round 18: full revert of R17's bf16
// r/k/v/g (absmax 0.055 > 0.02 — no quantization headroom). New: k_wkv_pre +
// k_wkv_kv fused into k_wkv_prekv with two-level parallel prefix over tau
// (kills the 64-step serial exp chain) and kt kept in LDS for the kv phase
// (-25MB re-read, -1 launch); qshift+wprep merged. B=8, T=1024, C=768, H=12.
// ---------------------------------------------------------------------------

#define EPI_NONE 0
#define EPI_TANH 1
#define EPI_RELU 2
#define EPI_BIAS 3

typedef float f32x4 __attribute__((ext_vector_type(4)));
typedef __bf16 bf16x8 __attribute__((ext_vector_type(8)));

__device__ __forceinline__ ushort f2bf(float x) {
  unsigned u = __float_as_uint(x);
  return (ushort)((u + 0x7fffu + ((u >> 16) & 1u)) >> 16);
}

#define GLDS16(gp, lp)                                                   \
  __builtin_amdgcn_global_load_lds(                                      \
      (const __attribute__((address_space(1))) void*)(gp),               \
      (__attribute__((address_space(3))) void*)(lp), 16, 0, 0)

// ---------------- fused qshift + weight transposes (one launch) ------------
__global__ __launch_bounds__(256) void k_prep(
    const float* __restrict__ x, const float* __restrict__ maa_x,
    ushort* __restrict__ xxx_bf,
    const float* __restrict__ w1, const float* __restrict__ w2,
    const float* __restrict__ dw1, const float* __restrict__ dw2,
    ushort* __restrict__ maa1T, ushort* __restrict__ w2T,
    ushort* __restrict__ w1dT, ushort* __restrict__ w2dT,
    int B, int T, int C, int ph, int pw) {
  long bx = blockIdx.x;
  const long QBLK = 24576;              // M*C/256
  if (bx < QBLK) {
    long idx = bx * 256 + threadIdx.x;
    int c = (int)(idx % C);
    long bt = idx / C;
    int t = (int)(bt % T);
    int quarter = (c & 63) >> 4;
    int hh = t / pw;
    int ww = t - hh * pw;
    long rowbase = (bt - t) * C;
    float sval = 0.f;
    int st = -1;
    if (quarter == 0)      { if (ww >= 1)      st = t - 1;  }
    else if (quarter == 1) { if (ww < pw - 1)  st = t + 1;  }
    else if (quarter == 2) { if (hh >= 1)      st = t - pw; }
    else                   { if (hh < ph - 1)  st = t + pw; }
    if (st >= 0) sval = x[rowbase + (long)st * C + c];
    float xval = x[idx];
    float d = sval - xval;
    xxx_bf[idx] = f2bf(xval + d * maa_x[c]);
    return;
  }
  int idx = (int)(bx - QBLK) * 256 + threadIdx.x;
  if (idx < 196608) {
    int n = idx / 768, k = idx - n * 768;
    maa1T[idx] = f2bf(n < 160 ? w1[(size_t)k * 160 + n] : 0.f);
  } else if (idx < 196608 + 122880) {
    int j = idx - 196608;
    int c = j / 160, kk = j - c * 160;
    w2T[j] = f2bf(w2[(size_t)kk * 768 + c]);
  } else if (idx < 196608 + 122880 + 98304) {
    int j = idx - (196608 + 122880);
    int n = j / 768, k = j - n * 768;
    w1dT[j] = f2bf(n < 64 ? dw1[(size_t)k * 64 + n] : 0.f);
  } else {
    int j = idx - (196608 + 122880 + 98304);
    int n = j >> 6, k = j & 63;
    w2dT[j] = f2bf(dw2[(size_t)k * 768 + n]);
  }
}

// --------------------------- mix5 on MFMA, no LDS, no barriers -------------
__global__ __launch_bounds__(256) void k_mix5m(
    const ushort* __restrict__ t5b, const ushort* __restrict__ w2T,
    const float* __restrict__ x,
    const float* __restrict__ maa_w, const float* __restrict__ maa_k,
    const float* __restrict__ maa_v, const float* __restrict__ maa_r,
    const float* __restrict__ maa_g,
    ushort* __restrict__ xw, ushort* __restrict__ xk, ushort* __restrict__ xvb,
    ushort* __restrict__ xr, ushort* __restrict__ xg,
    int C, int T, int ph, int pw) {
  int tid = threadIdx.x;
  int lane = tid & 63, wid = tid >> 6;
  int m0 = blockIdx.y * 64, n0 = blockIdx.x * 128;
  int lm = lane & 15, lk = (lane >> 4) * 8;
  int rq = (lane >> 4) * 4;
  const ushort* ap = t5b + (size_t)(m0 + wid * 16 + lm) * 160 + lk;

  int stq[4][4];
#pragma unroll
  for (int q = 0; q < 4; q++) {
    int mr = m0 + wid * 16 + rq + q;
    int t = mr % T;
    int hh = t / pw, ww = t - hh * pw;
    stq[q][0] = (ww >= 1)      ? mr - 1  : -1;
    stq[q][1] = (ww < pw - 1)  ? mr + 1  : -1;
    stq[q][2] = (hh >= 1)      ? mr - pw : -1;
    stq[q][3] = (hh < ph - 1)  ? mr + pw : -1;
  }

  float xh[8][4], dh[8][4];
#pragma unroll
  for (int j = 0; j < 8; j++)
#pragma unroll
    for (int q = 0; q < 4; q++) {
      int mr = m0 + wid * 16 + rq + q;
      int col = n0 + j * 16 + lm;
      float xv = x[(size_t)mr * C + col];
      int sr = stq[q][j & 3];
      float sv = (sr >= 0) ? x[(size_t)sr * C + col] : 0.f;
      xh[j][q] = xv;
      dh[j][q] = sv - xv;
    }

#pragma unroll
  for (int f = 0; f < 5; f++) {
    bf16x8 af = *(const bf16x8*)(ap + f * 32);
    f32x4 acc[8];
#pragma unroll
    for (int j = 0; j < 8; j++) {
      bf16x8 bfj = *(const bf16x8*)(w2T +
          (size_t)(n0 + j * 16 + lm) * 160 + f * 32 + lk);
      acc[j] = __builtin_amdgcn_mfma_f32_16x16x32_bf16(
          af, bfj, (f32x4){0.f, 0.f, 0.f, 0.f}, 0, 0, 0);
    }
    const float* maa_f = (f == 0) ? maa_w : (f == 1) ? maa_k
                        : (f == 2) ? maa_v : (f == 3) ? maa_r : maa_g;
    ushort* dst = (f == 0) ? xw : (f == 1) ? xk
                 : (f == 2) ? xvb : (f == 3) ? xr : xg;
#pragma unroll
    for (int j = 0; j < 8; j++) {
      float mf = maa_f[n0 + j * 16 + lm];
#pragma unroll
      for (int q = 0; q < 4; q++) {
        size_t off = (size_t)(m0 + wid * 16 + rq + q) * C + (n0 + j * 16 + lm);
        dst[off] = f2bf(xh[j][q] + dh[j][q] * (mf + acc[j][q]));
      }
    }
  }
}

// -------------------------------------------- fp32 -> bf16 cvt (5 arrays) --
__global__ __launch_bounds__(256) void k_cvt5(
    const float* __restrict__ s0, const float* __restrict__ s1,
    const float* __restrict__ s2, const float* __restrict__ s3,
    const float* __restrict__ s4,
    ushort* __restrict__ d0, ushort* __restrict__ d1,
    ushort* __restrict__ d2, ushort* __restrict__ d3,
    ushort* __restrict__ d4, int n) {
  const float* s;
  ushort* d;
  switch (blockIdx.y) {
    case 0: s = s0; d = d0; break;
    case 1: s = s1; d = d1; break;
    case 2: s = s2; d = d2; break;
    case 3: s = s3; d = d3; break;
    default: s = s4; d = d4; break;
  }
  int i = (blockIdx.x * 256 + threadIdx.x) * 4;
  if (i >= n) return;
  float4 v = *(const float4*)(s + i);
  ushort4 o;
  o.x = f2bf(v.x); o.y = f2bf(v.y); o.z = f2bf(v.z); o.w = f2bf(v.w);
  *(ushort4*)(d + i) = o;
}

// ----------------------------------------------------- bf16 MFMA GEMM ------
template <int EPI, bool NMASK, bool OBF16>
__global__ __launch_bounds__(256) void k_gemm_bf(
    const ushort* __restrict__ A, const ushort* __restrict__ W,
    const float* __restrict__ bias, void* __restrict__ Cm,
    int M, int N, int K) {
  __shared__ ushort Al[128 * 64];
  __shared__ ushort Bl[128 * 64];
  int nwg = gridDim.x * gridDim.y;
  int bid = blockIdx.y * gridDim.x + blockIdx.x;
  int swz = (nwg & 7) == 0 ? ((bid & 7) * (nwg >> 3) + (bid >> 3)) : bid;
  int bx = swz % gridDim.x, by = swz / gridDim.x;
  int m0 = by * 128, n0 = bx * 128;
  int tid = threadIdx.x;
  int lane = tid & 63, wave = tid >> 6;
  int wm = (wave >> 1) * 64, wn = (wave & 1) * 64;
  int lm = lane & 15, g = lane >> 4;
  f32x4 acc[4][4];
#pragma unroll
  for (int i = 0; i < 4; i++)
#pragma unroll
    for (int j = 0; j < 4; j++) acc[i][j] = (f32x4){0.f, 0.f, 0.f, 0.f};

  for (int k0 = 0; k0 < K; k0 += 64) {
#pragma unroll
    for (int i = 0; i < 4; i++) {
      int cid = tid + i * 256;             // 0..1023 16B-chunks
      int row = cid >> 3, p = cid & 7;
      int cq = p ^ (row & 7);
      GLDS16(A + (size_t)(m0 + row) * K + k0 + cq * 8, Al + cid * 8);
      GLDS16(W + (size_t)(n0 + row) * K + k0 + cq * 8, Bl + cid * 8);
    }
    __syncthreads();
#pragma unroll
    for (int s = 0; s < 2; s++) {
      bf16x8 af[4], bf[4];
#pragma unroll
      for (int i = 0; i < 4; i++) {
        int r = wm + i * 16 + lm;
        af[i] = *(const bf16x8*)&Al[r * 64 + (((s * 4 + g) ^ (r & 7)) * 8)];
        int rb = wn + i * 16 + lm;
        bf[i] = *(const bf16x8*)&Bl[rb * 64 + (((s * 4 + g) ^ (rb & 7)) * 8)];
      }
#pragma unroll
      for (int i = 0; i < 4; i++)
#pragma unroll
        for (int j = 0; j < 4; j++)
          acc[i][j] = __builtin_amdgcn_mfma_f32_16x16x32_bf16(
              af[i], bf[j], acc[i][j], 0, 0, 0);
    }
    __syncthreads();
  }
  int rq = (lane >> 4) * 4;
#pragma unroll
  for (int i = 0; i < 4; i++) {
#pragma unroll
    for (int j = 0; j < 4; j++) {
      int gn = n0 + wn + j * 16 + lm;
      if (NMASK && gn >= N) continue;
      float bv = (EPI == EPI_BIAS) ? bias[gn] : 0.f;
#pragma unroll
      for (int q = 0; q < 4; q++) {
        int gm = m0 + wm + i * 16 + rq + q;
        float val = acc[i][j][q];
        if (EPI == EPI_BIAS) val += bv;
        if (EPI == EPI_RELU) val = fmaxf(val, 0.f);
        if (EPI == EPI_TANH) val = tanhf(val);
        if (OBF16) ((ushort*)Cm)[(size_t)gm * N + gn] = f2bf(val);
        else       ((float*)Cm)[(size_t)gm * N + gn] = val;
      }
    }
  }
}

// --------------------------------- batched 4-projection bf16 MFMA GEMM -----
__global__ __launch_bounds__(256) void k_proj4(
    const ushort* __restrict__ A0, const ushort* __restrict__ A1,
    const ushort* __restrict__ A2, const ushort* __restrict__ A3,
    const ushort* __restrict__ W0, const ushort* __restrict__ W1,
    const ushort* __restrict__ W2, const ushort* __restrict__ W3,
    float* __restrict__ C0, float* __restrict__ C1,
    float* __restrict__ C2, float* __restrict__ C3,
    int M, int N, int K) {
  int nwg = gridDim.x;                       // 1536, %8==0
  int bid = blockIdx.x;
  int swz = (bid & 7) * (nwg >> 3) + (bid >> 3);
  int nxt = N / 128;                         // 6
  int per_z = (M / 128) * nxt;               // 384
  int z = swz / per_z;
  int rem = swz - z * per_z;
  int my = rem / nxt, nx = rem - my * nxt;
  const ushort* A = (z == 0) ? A0 : (z == 1) ? A1 : (z == 2) ? A2 : A3;
  const ushort* W = (z == 0) ? W0 : (z == 1) ? W1 : (z == 2) ? W2 : W3;
  float* Cm       = (z == 0) ? C0 : (z == 1) ? C1 : (z == 2) ? C2 : C3;
  __shared__ ushort Al[128 * 64];
  __shared__ ushort Bl[128 * 64];
  int tid = threadIdx.x;
  int m0 = my * 128, n0 = nx * 128;
  int lane = tid & 63, wave = tid >> 6;
  int wm = (wave >> 1) * 64, wn = (wave & 1) * 64;
  int lm = lane & 15, g = lane >> 4;
  f32x4 acc[4][4];
#pragma unroll
  for (int i = 0; i < 4; i++)
#pragma unroll
    for (int j = 0; j < 4; j++) acc[i][j] = (f32x4){0.f, 0.f, 0.f, 0.f};

  for (int k0 = 0; k0 < K; k0 += 64) {
#pragma unroll
    for (int i = 0; i < 4; i++) {
      int cid = tid + i * 256;
      int row = cid >> 3, p = cid & 7;
      int cq = p ^ (row & 7);
      GLDS16(A + (size_t)(m0 + row) * K + k0 + cq * 8, Al + cid * 8);
      GLDS16(W + (size_t)(n0 + row) * K + k0 + cq * 8, Bl + cid * 8);
    }
    __syncthreads();
#pragma unroll
    for (int s = 0; s < 2; s++) {
      bf16x8 af[4], bf[4];
#pragma unroll
      for (int i = 0; i < 4; i++) {
        int r = wm + i * 16 + lm;
        af[i] = *(const bf16x8*)&Al[r * 64 + (((s * 4 + g) ^ (r & 7)) * 8)];
        int rb = wn + i * 16 + lm;
        bf[i] = *(const bf16x8*)&Bl[rb * 64 + (((s * 4 + g) ^ (rb & 7)) * 8)];
      }
#pragma unroll
      for (int i = 0; i < 4; i++)
#pragma unroll
        for (int j = 0; j < 4; j++)
          acc[i][j] = __builtin_amdgcn_mfma_f32_16x16x32_bf16(
              af[i], bf[j], acc[i][j], 0, 0, 0);
    }
    __syncthreads();
  }
  bool relu = (z == 3);
  int rq = (lane >> 4) * 4;
#pragma unroll
  for (int i = 0; i < 4; i++) {
#pragma unroll
    for (int j = 0; j < 4; j++) {
      int gn = n0 + wn + j * 16 + lm;
#pragma unroll
      for (int q = 0; q < 4; q++) {
        int gm = m0 + wm + i * 16 + rq + q;
        float val = acc[i][j][q];
        if (relu) val = fmaxf(val, 0.f);
        Cm[(size_t)gm * N + gn] = val;
      }
    }
  }
}

// --------------- chunked WKV: fused pre (parallel prefix) + kv outer -------
// 256 threads: wave g owns taus [16g,16g+16), lane j = channel. Two-level
// prefix over tau (16-serial + LDS group combine) replaces the 64-step
// serial exp chain; kt tile stays in LDS for the kv phase (-25MB re-read).
__global__ __launch_bounds__(256) void k_wkv_prekv(
    const float* __restrict__ r, const float* __restrict__ k,
    const float* __restrict__ w, const float* __restrict__ u,
    const float* __restrict__ v,
    float* __restrict__ rt, float* __restrict__ kt,
    float* __restrict__ aL, float* __restrict__ pdiag,
    float* __restrict__ kvb, int B, int T, int C, int H, int L) {
  __shared__ float Ks[64 * 64];    // kt tile [tau][j]
  __shared__ float Vs[64 * 64];    // v tile
  __shared__ float pls[64 * 68];   // r*u*k products for pdiag
  __shared__ float gsum[4 * 64];   // per-group e-totals
  int nch = T / L;
  int blk = blockIdx.x;
  int bh = blk / nch, c = blk - bh * nch;
  int b = bh / H, h = bh - b * H;
  int tid = threadIdx.x;
  int gsel = tid >> 6;             // tau group 0..3
  int j = tid & 63;                // channel
  long cbase = ((long)b * T + (long)c * L) * C + h * 64;

  // async V -> Vs (consumed in kv phase; drained by first barrier chain)
#pragma unroll
  for (int i = 0; i < 4; i++) {
    int chunk = gsel * 4 + i;
    int row = chunk * 4 + (j >> 4);
    int cq = j & 15;
    GLDS16(v + cbase + (long)row * C + cq * 4, Vs + chunk * 256);
  }

  int tau0 = gsel * 16;
  float uj = u[h * 64 + j];
  float ev[16];
#pragma unroll
  for (int i = 0; i < 16; i++)
    ev[i] = expf(w[cbase + (long)(tau0 + i) * C + j]);
  float pre[16];
  float run = 0.f;
#pragma unroll
  for (int i = 0; i < 16; i++) { pre[i] = run; run += ev[i]; }
  gsum[gsel * 64 + j] = run;
  __syncthreads();
  float s0g = gsum[0 * 64 + j];
  float s1g = gsum[1 * 64 + j];
  float s2g = gsum[2 * 64 + j];
  float off0 = (gsel > 0 ? s0g : 0.f) + (gsel > 1 ? s1g : 0.f) +
               (gsel > 2 ? s2g : 0.f);
  if (gsel == 3)
    aL[((long)bh * nch + c) * 64 + j] = expf(-(off0 + run));

#pragma unroll
  for (int i = 0; i < 16; i++) {
    long offg = cbase + (long)(tau0 + i) * C + j;
    float rv = r[offg];
    float kv = k[offg];
    float ce = off0 + pre[i];              // exclusive prefix
    float rtv = rv * expf(-ce);
    float ktv = kv * expf(ce + ev[i]);     // inclusive prefix
    rt[offg] = rtv;
    kt[offg] = ktv;
    Ks[(tau0 + i) * 64 + j] = ktv;
    pls[(tau0 + i) * 68 + j] = rv * uj * kv;
  }
  __syncthreads();   // Ks, pls complete; Vs GLDS drained

  // pdiag: threads 0..63 sum row tau over channels
  if (tid < 64) {
    float s0 = 0.f, s1 = 0.f, s2 = 0.f, s3 = 0.f;
#pragma unroll
    for (int q = 0; q < 16; q++) {
      float4 p4 = *(const float4*)(pls + tid * 68 + q * 4);
      s0 += p4.x; s1 += p4.y; s2 += p4.z; s3 += p4.w;
    }
    pdiag[(long)bh * T + c * L + tid] = (s0 + s1) + (s2 + s3);
  }

  // kv phase: kvb[jk][i] = sum_s Ks[s][jk] * Vs[s][i]
  int lane = tid & 63, jg = tid >> 6;
  float acc[16];
#pragma unroll
  for (int q = 0; q < 16; q++) acc[q] = 0.f;
  for (int s = 0; s < 64; s++) {
    float vi = Vs[s * 64 + lane];
#pragma unroll
    for (int q4 = 0; q4 < 4; q4++) {
      float4 kk = *(const float4*)(Ks + s * 64 + jg * 16 + q4 * 4);
      acc[q4 * 4 + 0] = fmaf(kk.x, vi, acc[q4 * 4 + 0]);
      acc[q4 * 4 + 1] = fmaf(kk.y, vi, acc[q4 * 4 + 1]);
      acc[q4 * 4 + 2] = fmaf(kk.z, vi, acc[q4 * 4 + 2]);
      acc[q4 * 4 + 3] = fmaf(kk.w, vi, acc[q4 * 4 + 3]);
    }
  }
  float* out = kvb + ((long)bh * nch + c) * 4096;
#pragma unroll
  for (int q = 0; q < 16; q++) out[(jg * 16 + q) * 64 + lane] = acc[q];
}

// ---------------------------------------- chunked WKV: state prefix scan ---
__global__ __launch_bounds__(256) void k_wkv_scan(
    const float* __restrict__ kvb, const float* __restrict__ aL,
    float* __restrict__ Scb, int nch) {
  int bh = blockIdx.x >> 4;
  int e = ((blockIdx.x & 15) << 8) + threadIdx.x;   // 0..4095
  float S = 0.f;
  for (int c = 0; c < nch; c++) {
    long cb = ((long)bh * nch + c) * 4096 + e;
    Scb[cb] = S;
    S = aL[((long)bh * nch + c) * 64 + (e >> 6)] * (S + kvb[cb]);
  }
}

// ------------- chunked WKV: intra + inter + groupnorm*gate (fused) ---------
// R16 outer-product form: P^T from transposed-staged KtT/RtT; RtT doubles as
// passB operand; V,S direct from L2; 2 barriers.
__global__ __launch_bounds__(256, 3) void k_wkv_intra(
    const float* __restrict__ rt, const float* __restrict__ kt,
    const float* __restrict__ v, const float* __restrict__ pdiag,
    const float* __restrict__ Scb, const float* __restrict__ g,
    const float* __restrict__ ln_w, const float* __restrict__ ln_b,
    ushort* __restrict__ z, int B, int T, int C, int H, int L) {
  int nch = T / L;
  int blk = blockIdx.x;
  int bh = blk / nch, c = blk - bh * nch;
  int b = bh / H, h = bh - b * H;
  __shared__ float KtT[64 * 68];   // [chan][time]
  __shared__ float RtT[64 * 68];   // [chan][time] (also passB operand)
  __shared__ float Pt[64 * 68];    // P^T [s][tau]
  int tid = threadIdx.x;
  int lane = tid & 63, wid = tid >> 6;
  long cbase = ((long)b * T + (long)c * L) * C + h * 64;
  const float* scp = Scb + ((long)bh * nch + c) * 4096;

  // --- stage: reg-transpose Kt,Rt -> KtT,RtT ---
  {
    int t0 = (tid >> 4) * 4;        // time group
    int c0s = (tid & 15) * 4;       // chan group
    float4 ka[4], ra[4];
#pragma unroll
    for (int i = 0; i < 4; i++) {
      ka[i] = *(const float4*)(kt + cbase + (long)(t0 + i) * C + c0s);
      ra[i] = *(const float4*)(rt + cbase + (long)(t0 + i) * C + c0s);
    }
#pragma unroll
    for (int j = 0; j < 4; j++) {
      float4 ko, ro;
      ko.x = ka[0][j]; ko.y = ka[1][j]; ko.z = ka[2][j]; ko.w = ka[3][j];
      ro.x = ra[0][j]; ro.y = ra[1][j]; ro.z = ra[2][j]; ro.w = ra[3][j];
      *(float4*)(KtT + (c0s + j) * 68 + t0) = ko;
      *(float4*)(RtT + (c0s + j) * 68 + t0) = ro;
    }
  }
  __syncthreads();                                           // b1

  // --- phase 1: outer-product P^T[s0..3][tau0..3] ---
  {
    int s0 = (tid >> 4) * 4;
    int tau0 = (tid & 15) * 4;
    float4 pd4 = *(const float4*)(pdiag + (long)bh * T + c * L + tau0);
    float p00 = 0.f, p01 = 0.f, p02 = 0.f, p03 = 0.f;
    float p10 = 0.f, p11 = 0.f, p12 = 0.f, p13 = 0.f;
    float p20 = 0.f, p21 = 0.f, p22 = 0.f, p23 = 0.f;
    float p30 = 0.f, p31 = 0.f, p32 = 0.f, p33 = 0.f;
#pragma unroll 4
    for (int cc = 0; cc < 64; cc++) {
      float4 kq = *(const float4*)(KtT + cc * 68 + s0);
      float4 rq = *(const float4*)(RtT + cc * 68 + tau0);
      p00 = fmaf(kq.x, rq.x, p00); p01 = fmaf(kq.x, rq.y, p01);
      p02 = fmaf(kq.x, rq.z, p02); p03 = fmaf(kq.x, rq.w, p03);
      p10 = fmaf(kq.y, rq.x, p10); p11 = fmaf(kq.y, rq.y, p11);
      p12 = fmaf(kq.y, rq.z, p12); p13 = fmaf(kq.y, rq.w, p13);
      p20 = fmaf(kq.z, rq.x, p20); p21 = fmaf(kq.z, rq.y, p21);
      p22 = fmaf(kq.z, rq.z, p22); p23 = fmaf(kq.z, rq.w, p23);
      p30 = fmaf(kq.w, rq.x, p30); p31 = fmaf(kq.w, rq.y, p31);
      p32 = fmaf(kq.w, rq.z, p32); p33 = fmaf(kq.w, rq.w, p33);
    }
#define PMASK(PI0, PI1, PI2, PI3, I)                                       \
    {                                                                      \
      int s = s0 + (I);                                                    \
      float4 o;                                                            \
      o.x = (s < tau0 + 0) ? PI0 : (s == tau0 + 0 ? pd4.x : 0.f);          \
      o.y = (s < tau0 + 1) ? PI1 : (s == tau0 + 1 ? pd4.y : 0.f);          \
      o.z = (s < tau0 + 2) ? PI2 : (s == tau0 + 2 ? pd4.z : 0.f);          \
      o.w = (s < tau0 + 3) ? PI3 : (s == tau0 + 3 ? pd4.w : 0.f);          \
      *(float4*)(Pt + s * 68 + tau0) = o;                                  \
    }
    PMASK(p00, p01, p02, p03, 0)
    PMASK(p10, p11, p12, p13, 1)
    PMASK(p20, p21, p22, p23, 2)
    PMASK(p30, p31, p32, p33, 3)
#undef PMASK
  }
  __syncthreads();                                           // b2

  // --- fused pass: Y = P^T(row0..3) . V  +  RtT(row0..3) . S ---
  int row0 = wid * 16 + ((lane >> 4) << 2);   // 4 output taus
  int c0v = (lane & 15) * 4;                  // 4 output chans
  float4 acc0 = {0.f, 0.f, 0.f, 0.f};
  float4 acc1 = {0.f, 0.f, 0.f, 0.f};
  float4 acc2 = {0.f, 0.f, 0.f, 0.f};
  float4 acc3 = {0.f, 0.f, 0.f, 0.f};
  const float* vp = v + cbase + c0v;
#define FMA2(A, P, V4, R, S4)                          \
  A.x = fmaf(P, V4.x, fmaf(R, S4.x, A.x));             \
  A.y = fmaf(P, V4.y, fmaf(R, S4.y, A.y));             \
  A.z = fmaf(P, V4.z, fmaf(R, S4.z, A.z));             \
  A.w = fmaf(P, V4.w, fmaf(R, S4.w, A.w));
#pragma unroll 4
  for (int j = 0; j < 64; j++) {
    float4 pp = *(const float4*)(Pt + j * 68 + row0);    // 16-lane multicast
    float4 rr = *(const float4*)(RtT + j * 68 + row0);   // 16-lane multicast
    float4 vv = *(const float4*)(vp + (long)j * C);      // L2, 256B/wave
    float4 ssv = *(const float4*)(scp + j * 64 + c0v);   // L2, 256B/wave
    FMA2(acc0, pp.x, vv, rr.x, ssv);
    FMA2(acc1, pp.y, vv, rr.y, ssv);
    FMA2(acc2, pp.z, vv, rr.z, ssv);
    FMA2(acc3, pp.w, vv, rr.w, ssv);
  }
#undef FMA2

  // ---- fused groupnorm (per row over this head's 64 channels) * gate ----
  float4 lw4 = *(const float4*)(ln_w + h * 64 + c0v);
  float4 lb4 = *(const float4*)(ln_b + h * 64 + c0v);
#define GNROW(A, m)                                                        \
  {                                                                        \
    float s1 = (A.x + A.y) + (A.z + A.w);                                  \
    s1 += __shfl_xor(s1, 1, 64);                                           \
    s1 += __shfl_xor(s1, 2, 64);                                           \
    s1 += __shfl_xor(s1, 4, 64);                                           \
    s1 += __shfl_xor(s1, 8, 64);                                           \
    float mu = s1 * (1.f / 64.f);                                          \
    float4 dd;                                                             \
    dd.x = A.x - mu; dd.y = A.y - mu; dd.z = A.z - mu; dd.w = A.w - mu;    \
    float s2 = (dd.x * dd.x + dd.y * dd.y) + (dd.z * dd.z + dd.w * dd.w);  \
    s2 += __shfl_xor(s2, 1, 64);                                           \
    s2 += __shfl_xor(s2, 2, 64);                                           \
    s2 += __shfl_xor(s2, 4, 64);                                           \
    s2 += __shfl_xor(s2, 8, 64);                                           \
    float rstd = rsqrtf(s2 * (1.f / 64.f) + 1e-5f);                        \
    long off = cbase + (long)(row0 + m) * C + c0v;                         \
    float4 g4 = *(const float4*)(g + off);                                 \
    ushort4 ob;                                                            \
    ob.x = f2bf((dd.x * rstd * lw4.x + lb4.x) * g4.x);                     \
    ob.y = f2bf((dd.y * rstd * lw4.y + lb4.y) * g4.y);                     \
    ob.z = f2bf((dd.z * rstd * lw4.z + lb4.z) * g4.z);                     \
    ob.w = f2bf((dd.w * rstd * lw4.w + lb4.w) * g4.w);                     \
    *(ushort4*)(z + off) = ob;                                             \
  }
  GNROW(acc0, 0)
  GNROW(acc1, 1)
  GNROW(acc2, 2)
  GNROW(acc3, 3)
#undef GNROW
}

// ---------------------------------------------------------------- launch ---
extern "C" void kernel_launch(void* const* d_in, const int* in_sizes, int n_in,
                              void* d_out, int out_size, void* d_ws, size_t ws_size,
                              hipStream_t stream) {
  const int B = 8, T = 1024, C = 768, H = 12, ph = 32, pw = 32;
  const int M = B * T;
  const int L = 64, NCH = T / L;

  const float* x        = (const float*)d_in[0];
  const float* W_r      = (const float*)d_in[1];
  const float* W_k      = (const float*)d_in[2];
  const float* W_v      = (const float*)d_in[3];
  const float* W_g      = (const float*)d_in[4];
  const float* W_o      = (const float*)d_in[5];
  const float* maa_x    = (const float*)d_in[6];
  const float* maa_w    = (const float*)d_in[7];
  const float* maa_k    = (const float*)d_in[8];
  const float* maa_v    = (const float*)d_in[9];
  const float* maa_r    = (const float*)d_in[10];
  const float* maa_g    = (const float*)d_in[11];
  const float* maa_w1   = (const float*)d_in[12];
  const float* maa_w2   = (const float*)d_in[13];
  const float* time_dec = (const float*)d_in[14];
  const float* dec_w1   = (const float*)d_in[15];
  const float* dec_w2   = (const float*)d_in[16];
  const float* faaaa    = (const float*)d_in[17];
  const float* ln_w     = (const float*)d_in[18];
  const float* ln_b     = (const float*)d_in[19];

  float* ws = (float*)d_ws;
  const size_t S = (size_t)M * C;
  float* F0 = ws + 0 * S;   // r (fp32)
  float* F1 = ws + 1 * S;   // xxx_bf -> k -> Scb
  float* F2 = ws + 2 * S;   // xw_bf -> w -> Kt (in place)
  float* F3 = ws + 3 * S;   // v (fp32)
  float* F4 = ws + 4 * S;   // g (fp32)
  float* F5 = ws + 5 * S;   // xr_bf | xk_bf -> Rt (fp32)
  float* F6 = ws + 6 * S;   // xv_bf | xg_bf -> kvb -> z_bf
  float* t5    = ws + 7 * S;            // [M,160] bf16 t5b -> bf16 W_r..W_g
  float* t6    = t5 + (size_t)M * 160;  // bf16 W_o + maa1T + decT
  float* aLb   = t6 + (size_t)M * 64;
  float* pdiag = aLb + (size_t)B * H * NCH * 64;
  float* dec_t = pdiag + (size_t)B * H * T;   // [M,64] t_bf + w2T scratch

  ushort* xxx_bf = (ushort*)F1;
  ushort* xw_bf = (ushort*)F2;
  ushort* xr_bf = (ushort*)F5;
  ushort* xk_bf = xr_bf + S;
  ushort* xv_bf = (ushort*)F6;
  ushort* xg_bf = xv_bf + S;
  float*  kvb   = F6;                   // dead xv/xg space; dead after scan
  ushort* z_bf  = (ushort*)F6;          // intra output (after scan)
  ushort* t5b   = (ushort*)t5;          // [M,160] bf16
  ushort* t_bf  = (ushort*)dec_t;       // [M,64] bf16
  ushort* w2T   = t_bf + (size_t)M * 64;  // [768,160] bf16 (dead after mix5)
  float* Scb = F1;
  const int WSZ = C * C;
  ushort* wr_bf = (ushort*)t5;
  ushort* wk_bf = wr_bf + WSZ;
  ushort* wv_bf = wk_bf + WSZ;
  ushort* wg_bf = wv_bf + WSZ;
  ushort* wo_bf = (ushort*)t6;
  ushort* maa1T = wo_bf + WSZ;          // [256,768]
  ushort* w1dT  = maa1T + 256 * 768;    // [128,768]
  ushort* w2dT  = w1dT + 128 * 768;     // [768,64]

  // 1. fused qshift + weight transposes (one launch)
  {
    k_prep<<<24576 + 1824, 256, 0, stream>>>(
        x, maa_x, xxx_bf, maa_w1, maa_w2, dec_w1, dec_w2,
        maa1T, w2T, w1dT, w2dT, B, T, C, ph, pw);
  }
  // 2. t5b = tanh(xxx @ maa_w1) via MFMA (bf16 out)
  {
    dim3 grid(2, M / 128);
    k_gemm_bf<EPI_TANH, true, true><<<grid, 256, 0, stream>>>(
        xxx_bf, maa1T, nullptr, t5b, M, 160, C);
  }
  // 3. mix5 on MFMA (all outputs bf16; dh inline)
  {
    dim3 grid(C / 128, M / 64);
    k_mix5m<<<grid, 256, 0, stream>>>(t5b, w2T, x, maa_w, maa_k, maa_v,
                                      maa_r, maa_g, xw_bf, xk_bf, xv_bf, xr_bf,
                                      xg_bf, C, T, ph, pw);
  }
  // 4. weight conversion (t5b data dead now)
  {
    dim3 grid((WSZ / 4 + 255) / 256, 5);
    k_cvt5<<<grid, 256, 0, stream>>>(W_r, W_k, W_v, W_g, W_o,
                                     wr_bf, wk_bf, wv_bf, wg_bf, wo_bf, WSZ);
  }
  // 5. big projections -> fp32 r,k,v,g (1536 blocks, 1D)
  {
    k_proj4<<<(C / 128) * (M / 128) * 4, 256, 0, stream>>>(
        xr_bf, xk_bf, xv_bf, xg_bf, wr_bf, wk_bf, wv_bf, wg_bf,
        F0, F1, F3, F4, M, C, C);
  }
  // 6. decay path on MFMA (w fp32)
  {
    dim3 g1(1, M / 128);
    k_gemm_bf<EPI_TANH, true, true><<<g1, 256, 0, stream>>>(
        xw_bf, w1dT, nullptr, t_bf, M, 64, C);
    dim3 g2(C / 128, M / 128);
    k_gemm_bf<EPI_BIAS, false, false><<<g2, 256, 0, stream>>>(
        t_bf, w2dT, time_dec, F2, M, C, 64);
  }
  // 7. chunked wkv6: prekv (fused) -> scan -> intra(+GN+gate -> z bf16)
  k_wkv_prekv<<<B * H * NCH, 256, 0, stream>>>(
      F0, F1, F2, faaaa, F3, F5, F2, aLb, pdiag, kvb, B, T, C, H, L);
  k_wkv_scan<<<B * H * 16, 256, 0, stream>>>(kvb, aLb, Scb, NCH);
  k_wkv_intra<<<B * H * NCH, 256, 0, stream>>>(
      F5, F2, F3, pdiag, Scb, F4, ln_w, ln_b, z_bf, B, T, C, H, L);
  // 8. out = z @ W_o^T (bf16 MFMA)
  {
    dim3 grid(C / 128, M / 128);
    k_gemm_bf<EPI_NONE, false, false><<<grid, 256, 0, stream>>>(
        z_bf, wo_bf, nullptr, (float*)d_out, M, C, C);
  }
}

// Round 10
// 356.875 us; speedup vs baseline: 1.1815x; 1.0739x over previous
//
#include <hip/hip_runtime.h>
#include <math.h>

// ---------------------------------------------------------------------------
// TimeMix (RWKV-6 vision block) — round 19: rt/kt global round-trip deleted
// (intra recomputes the prefix from r,k,w and writes KtT/RtT transposed
// directly; prekv slims to k,w,v -> kvb,aL: -100MB traffic). Decay GEMM-1
// (64-block, latency-exposed) absorbed into proj4 as z=4. Scb relocated to
// F5 (k=F1 must survive scan). B=8, T=1024, C=768, H=12.
// ---------------------------------------------------------------------------

#define EPI_NONE 0
#define EPI_TANH 1
#define EPI_RELU 2
#define EPI_BIAS 3

typedef float f32x4 __attribute__((ext_vector_type(4)));
typedef __bf16 bf16x8 __attribute__((ext_vector_type(8)));

__device__ __forceinline__ ushort f2bf(float x) {
  unsigned u = __float_as_uint(x);
  return (ushort)((u + 0x7fffu + ((u >> 16) & 1u)) >> 16);
}

#define GLDS16(gp, lp)                                                   \
  __builtin_amdgcn_global_load_lds(                                      \
      (const __attribute__((address_space(1))) void*)(gp),               \
      (__attribute__((address_space(3))) void*)(lp), 16, 0, 0)

// ---------------- fused qshift + weight transposes (one launch) ------------
__global__ __launch_bounds__(256) void k_prep(
    const float* __restrict__ x, const float* __restrict__ maa_x,
    ushort* __restrict__ xxx_bf,
    const float* __restrict__ w1, const float* __restrict__ w2,
    const float* __restrict__ dw1, const float* __restrict__ dw2,
    ushort* __restrict__ maa1T, ushort* __restrict__ w2T,
    ushort* __restrict__ w1dT, ushort* __restrict__ w2dT,
    int B, int T, int C, int ph, int pw) {
  long bx = blockIdx.x;
  const long QBLK = 24576;              // M*C/256
  if (bx < QBLK) {
    long idx = bx * 256 + threadIdx.x;
    int c = (int)(idx % C);
    long bt = idx / C;
    int t = (int)(bt % T);
    int quarter = (c & 63) >> 4;
    int hh = t / pw;
    int ww = t - hh * pw;
    long rowbase = (bt - t) * C;
    float sval = 0.f;
    int st = -1;
    if (quarter == 0)      { if (ww >= 1)      st = t - 1;  }
    else if (quarter == 1) { if (ww < pw - 1)  st = t + 1;  }
    else if (quarter == 2) { if (hh >= 1)      st = t - pw; }
    else                   { if (hh < ph - 1)  st = t + pw; }
    if (st >= 0) sval = x[rowbase + (long)st * C + c];
    float xval = x[idx];
    float d = sval - xval;
    xxx_bf[idx] = f2bf(xval + d * maa_x[c]);
    return;
  }
  int idx = (int)(bx - QBLK) * 256 + threadIdx.x;
  if (idx < 196608) {
    int n = idx / 768, k = idx - n * 768;
    maa1T[idx] = f2bf(n < 160 ? w1[(size_t)k * 160 + n] : 0.f);
  } else if (idx < 196608 + 122880) {
    int j = idx - 196608;
    int c = j / 160, kk = j - c * 160;
    w2T[j] = f2bf(w2[(size_t)kk * 768 + c]);
  } else if (idx < 196608 + 122880 + 98304) {
    int j = idx - (196608 + 122880);
    int n = j / 768, k = j - n * 768;
    w1dT[j] = f2bf(n < 64 ? dw1[(size_t)k * 64 + n] : 0.f);
  } else {
    int j = idx - (196608 + 122880 + 98304);
    int n = j >> 6, k = j & 63;
    w2dT[j] = f2bf(dw2[(size_t)k * 768 + n]);
  }
}

// --------------------------- mix5 on MFMA, no LDS, no barriers -------------
__global__ __launch_bounds__(256) void k_mix5m(
    const ushort* __restrict__ t5b, const ushort* __restrict__ w2T,
    const float* __restrict__ x,
    const float* __restrict__ maa_w, const float* __restrict__ maa_k,
    const float* __restrict__ maa_v, const float* __restrict__ maa_r,
    const float* __restrict__ maa_g,
    ushort* __restrict__ xw, ushort* __restrict__ xk, ushort* __restrict__ xvb,
    ushort* __restrict__ xr, ushort* __restrict__ xg,
    int C, int T, int ph, int pw) {
  int tid = threadIdx.x;
  int lane = tid & 63, wid = tid >> 6;
  int m0 = blockIdx.y * 64, n0 = blockIdx.x * 128;
  int lm = lane & 15, lk = (lane >> 4) * 8;
  int rq = (lane >> 4) * 4;
  const ushort* ap = t5b + (size_t)(m0 + wid * 16 + lm) * 160 + lk;

  int stq[4][4];
#pragma unroll
  for (int q = 0; q < 4; q++) {
    int mr = m0 + wid * 16 + rq + q;
    int t = mr % T;
    int hh = t / pw, ww = t - hh * pw;
    stq[q][0] = (ww >= 1)      ? mr - 1  : -1;
    stq[q][1] = (ww < pw - 1)  ? mr + 1  : -1;
    stq[q][2] = (hh >= 1)      ? mr - pw : -1;
    stq[q][3] = (hh < ph - 1)  ? mr + pw : -1;
  }

  float xh[8][4], dh[8][4];
#pragma unroll
  for (int j = 0; j < 8; j++)
#pragma unroll
    for (int q = 0; q < 4; q++) {
      int mr = m0 + wid * 16 + rq + q;
      int col = n0 + j * 16 + lm;
      float xv = x[(size_t)mr * C + col];
      int sr = stq[q][j & 3];
      float sv = (sr >= 0) ? x[(size_t)sr * C + col] : 0.f;
      xh[j][q] = xv;
      dh[j][q] = sv - xv;
    }

#pragma unroll
  for (int f = 0; f < 5; f++) {
    bf16x8 af = *(const bf16x8*)(ap + f * 32);
    f32x4 acc[8];
#pragma unroll
    for (int j = 0; j < 8; j++) {
      bf16x8 bfj = *(const bf16x8*)(w2T +
          (size_t)(n0 + j * 16 + lm) * 160 + f * 32 + lk);
      acc[j] = __builtin_amdgcn_mfma_f32_16x16x32_bf16(
          af, bfj, (f32x4){0.f, 0.f, 0.f, 0.f}, 0, 0, 0);
    }
    const float* maa_f = (f == 0) ? maa_w : (f == 1) ? maa_k
                        : (f == 2) ? maa_v : (f == 3) ? maa_r : maa_g;
    ushort* dst = (f == 0) ? xw : (f == 1) ? xk
                 : (f == 2) ? xvb : (f == 3) ? xr : xg;
#pragma unroll
    for (int j = 0; j < 8; j++) {
      float mf = maa_f[n0 + j * 16 + lm];
#pragma unroll
      for (int q = 0; q < 4; q++) {
        size_t off = (size_t)(m0 + wid * 16 + rq + q) * C + (n0 + j * 16 + lm);
        dst[off] = f2bf(xh[j][q] + dh[j][q] * (mf + acc[j][q]));
      }
    }
  }
}

// -------------------------------------------- fp32 -> bf16 cvt (5 arrays) --
__global__ __launch_bounds__(256) void k_cvt5(
    const float* __restrict__ s0, const float* __restrict__ s1,
    const float* __restrict__ s2, const float* __restrict__ s3,
    const float* __restrict__ s4,
    ushort* __restrict__ d0, ushort* __restrict__ d1,
    ushort* __restrict__ d2, ushort* __restrict__ d3,
    ushort* __restrict__ d4, int n) {
  const float* s;
  ushort* d;
  switch (blockIdx.y) {
    case 0: s = s0; d = d0; break;
    case 1: s = s1; d = d1; break;
    case 2: s = s2; d = d2; break;
    case 3: s = s3; d = d3; break;
    default: s = s4; d = d4; break;
  }
  int i = (blockIdx.x * 256 + threadIdx.x) * 4;
  if (i >= n) return;
  float4 v = *(const float4*)(s + i);
  ushort4 o;
  o.x = f2bf(v.x); o.y = f2bf(v.y); o.z = f2bf(v.z); o.w = f2bf(v.w);
  *(ushort4*)(d + i) = o;
}

// ----------------------------------------------------- bf16 MFMA GEMM ------
template <int EPI, bool NMASK, bool OBF16>
__global__ __launch_bounds__(256) void k_gemm_bf(
    const ushort* __restrict__ A, const ushort* __restrict__ W,
    const float* __restrict__ bias, void* __restrict__ Cm,
    int M, int N, int K) {
  __shared__ ushort Al[128 * 64];
  __shared__ ushort Bl[128 * 64];
  int nwg = gridDim.x * gridDim.y;
  int bid = blockIdx.y * gridDim.x + blockIdx.x;
  int swz = (nwg & 7) == 0 ? ((bid & 7) * (nwg >> 3) + (bid >> 3)) : bid;
  int bx = swz % gridDim.x, by = swz / gridDim.x;
  int m0 = by * 128, n0 = bx * 128;
  int tid = threadIdx.x;
  int lane = tid & 63, wave = tid >> 6;
  int wm = (wave >> 1) * 64, wn = (wave & 1) * 64;
  int lm = lane & 15, g = lane >> 4;
  f32x4 acc[4][4];
#pragma unroll
  for (int i = 0; i < 4; i++)
#pragma unroll
    for (int j = 0; j < 4; j++) acc[i][j] = (f32x4){0.f, 0.f, 0.f, 0.f};

  for (int k0 = 0; k0 < K; k0 += 64) {
#pragma unroll
    for (int i = 0; i < 4; i++) {
      int cid = tid + i * 256;             // 0..1023 16B-chunks
      int row = cid >> 3, p = cid & 7;
      int cq = p ^ (row & 7);
      GLDS16(A + (size_t)(m0 + row) * K + k0 + cq * 8, Al + cid * 8);
      GLDS16(W + (size_t)(n0 + row) * K + k0 + cq * 8, Bl + cid * 8);
    }
    __syncthreads();
#pragma unroll
    for (int s = 0; s < 2; s++) {
      bf16x8 af[4], bf[4];
#pragma unroll
      for (int i = 0; i < 4; i++) {
        int r = wm + i * 16 + lm;
        af[i] = *(const bf16x8*)&Al[r * 64 + (((s * 4 + g) ^ (r & 7)) * 8)];
        int rb = wn + i * 16 + lm;
        bf[i] = *(const bf16x8*)&Bl[rb * 64 + (((s * 4 + g) ^ (rb & 7)) * 8)];
      }
#pragma unroll
      for (int i = 0; i < 4; i++)
#pragma unroll
        for (int j = 0; j < 4; j++)
          acc[i][j] = __builtin_amdgcn_mfma_f32_16x16x32_bf16(
              af[i], bf[j], acc[i][j], 0, 0, 0);
    }
    __syncthreads();
  }
  int rq = (lane >> 4) * 4;
#pragma unroll
  for (int i = 0; i < 4; i++) {
#pragma unroll
    for (int j = 0; j < 4; j++) {
      int gn = n0 + wn + j * 16 + lm;
      if (NMASK && gn >= N) continue;
      float bv = (EPI == EPI_BIAS) ? bias[gn] : 0.f;
#pragma unroll
      for (int q = 0; q < 4; q++) {
        int gm = m0 + wm + i * 16 + rq + q;
        float val = acc[i][j][q];
        if (EPI == EPI_BIAS) val += bv;
        if (EPI == EPI_RELU) val = fmaxf(val, 0.f);
        if (EPI == EPI_TANH) val = tanhf(val);
        if (OBF16) ((ushort*)Cm)[(size_t)gm * N + gn] = f2bf(val);
        else       ((float*)Cm)[(size_t)gm * N + gn] = val;
      }
    }
  }
}

// ------------- batched 4-projection + decay-1 bf16 MFMA GEMM (z=4) ---------
// z<4: r/k/v/g fp32 out. z=4: t = tanh(xw @ w1dT) -> bf16 [M,64] (the old
// 64-block latency-exposed decay GEMM rides along the big dispatch).
__global__ __launch_bounds__(256) void k_proj4(
    const ushort* __restrict__ A0, const ushort* __restrict__ A1,
    const ushort* __restrict__ A2, const ushort* __restrict__ A3,
    const ushort* __restrict__ A4,
    const ushort* __restrict__ W0, const ushort* __restrict__ W1,
    const ushort* __restrict__ W2, const ushort* __restrict__ W3,
    const ushort* __restrict__ W4,
    float* __restrict__ C0, float* __restrict__ C1,
    float* __restrict__ C2, float* __restrict__ C3,
    ushort* __restrict__ C4,
    int M, int N, int K) {
  int nwg = gridDim.x;                       // 1600, %8==0
  int bid = blockIdx.x;
  int swz = (bid & 7) * (nwg >> 3) + (bid >> 3);
  int nxt = N / 128;                         // 6
  int per_z = (M / 128) * nxt;               // 384
  int z, my, nx;
  if (swz < 4 * per_z) {
    z = swz / per_z;
    int rem = swz - z * per_z;
    my = rem / nxt; nx = rem - my * nxt;
  } else {
    z = 4; my = swz - 4 * per_z; nx = 0;     // 64 decay tiles
  }
  const ushort* A = (z == 0) ? A0 : (z == 1) ? A1 : (z == 2) ? A2
                  : (z == 3) ? A3 : A4;
  const ushort* W = (z == 0) ? W0 : (z == 1) ? W1 : (z == 2) ? W2
                  : (z == 3) ? W3 : W4;
  __shared__ ushort Al[128 * 64];
  __shared__ ushort Bl[128 * 64];
  int tid = threadIdx.x;
  int m0 = my * 128, n0 = nx * 128;
  int lane = tid & 63, wave = tid >> 6;
  int wm = (wave >> 1) * 64, wn = (wave & 1) * 64;
  int lm = lane & 15, g = lane >> 4;
  f32x4 acc[4][4];
#pragma unroll
  for (int i = 0; i < 4; i++)
#pragma unroll
    for (int j = 0; j < 4; j++) acc[i][j] = (f32x4){0.f, 0.f, 0.f, 0.f};

  for (int k0 = 0; k0 < K; k0 += 64) {
#pragma unroll
    for (int i = 0; i < 4; i++) {
      int cid = tid + i * 256;
      int row = cid >> 3, p = cid & 7;
      int cq = p ^ (row & 7);
      GLDS16(A + (size_t)(m0 + row) * K + k0 + cq * 8, Al + cid * 8);
      GLDS16(W + (size_t)(n0 + row) * K + k0 + cq * 8, Bl + cid * 8);
    }
    __syncthreads();
#pragma unroll
    for (int s = 0; s < 2; s++) {
      bf16x8 af[4], bf[4];
#pragma unroll
      for (int i = 0; i < 4; i++) {
        int r = wm + i * 16 + lm;
        af[i] = *(const bf16x8*)&Al[r * 64 + (((s * 4 + g) ^ (r & 7)) * 8)];
        int rb = wn + i * 16 + lm;
        bf[i] = *(const bf16x8*)&Bl[rb * 64 + (((s * 4 + g) ^ (rb & 7)) * 8)];
      }
#pragma unroll
      for (int i = 0; i < 4; i++)
#pragma unroll
        for (int j = 0; j < 4; j++)
          acc[i][j] = __builtin_amdgcn_mfma_f32_16x16x32_bf16(
              af[i], bf[j], acc[i][j], 0, 0, 0);
    }
    __syncthreads();
  }
  int rq = (lane >> 4) * 4;
  if (z == 4) {
#pragma unroll
    for (int i = 0; i < 4; i++)
#pragma unroll
      for (int j = 0; j < 4; j++) {
        int gn = wn + j * 16 + lm;           // n0 == 0
        if (gn >= 64) continue;
#pragma unroll
        for (int q = 0; q < 4; q++) {
          int gm = m0 + wm + i * 16 + rq + q;
          C4[(size_t)gm * 64 + gn] = f2bf(tanhf(acc[i][j][q]));
        }
      }
    return;
  }
  float* Cm = (z == 0) ? C0 : (z == 1) ? C1 : (z == 2) ? C2 : C3;
  bool relu = (z == 3);
#pragma unroll
  for (int i = 0; i < 4; i++) {
#pragma unroll
    for (int j = 0; j < 4; j++) {
      int gn = n0 + wn + j * 16 + lm;
#pragma unroll
      for (int q = 0; q < 4; q++) {
        int gm = m0 + wm + i * 16 + rq + q;
        float val = acc[i][j][q];
        if (relu) val = fmaxf(val, 0.f);
        Cm[(size_t)gm * N + gn] = val;
      }
    }
  }
}

// -------- chunked WKV: slim prekv (k,w,v -> kvb, aL; kt LDS-only) ----------
__global__ __launch_bounds__(256) void k_wkv_prekv(
    const float* __restrict__ k, const float* __restrict__ w,
    const float* __restrict__ v,
    float* __restrict__ aL, float* __restrict__ kvb,
    int B, int T, int C, int H, int L) {
  __shared__ float Ks[64 * 64];    // kt tile [tau][j]
  __shared__ float Vs[64 * 64];    // v tile
  __shared__ float gsum[4 * 64];   // per-group e-totals
  int nch = T / L;
  int blk = blockIdx.x;
  int bh = blk / nch, c = blk - bh * nch;
  int b = bh / H, h = bh - b * H;
  int tid = threadIdx.x;
  int gsel = tid >> 6;             // tau group 0..3
  int j = tid & 63;                // channel
  long cbase = ((long)b * T + (long)c * L) * C + h * 64;

  // async V -> Vs
#pragma unroll
  for (int i = 0; i < 4; i++) {
    int chunk = gsel * 4 + i;
    int row = chunk * 4 + (j >> 4);
    int cq = j & 15;
    GLDS16(v + cbase + (long)row * C + cq * 4, Vs + chunk * 256);
  }

  int tau0 = gsel * 16;
  float ev[16];
#pragma unroll
  for (int i = 0; i < 16; i++)
    ev[i] = expf(w[cbase + (long)(tau0 + i) * C + j]);
  float pre[16];
  float run = 0.f;
#pragma unroll
  for (int i = 0; i < 16; i++) { pre[i] = run; run += ev[i]; }
  gsum[gsel * 64 + j] = run;
  __syncthreads();
  float off0 = (gsel > 0 ? gsum[j] : 0.f) +
               (gsel > 1 ? gsum[64 + j] : 0.f) +
               (gsel > 2 ? gsum[128 + j] : 0.f);
  if (gsel == 3)
    aL[((long)bh * nch + c) * 64 + j] = expf(-(off0 + run));

#pragma unroll
  for (int i = 0; i < 16; i++) {
    float kv = k[cbase + (long)(tau0 + i) * C + j];
    Ks[(tau0 + i) * 64 + j] = kv * expf(off0 + pre[i] + ev[i]);
  }
  __syncthreads();   // Ks complete; Vs GLDS drained

  // kv phase: kvb[jk][i] = sum_s Ks[s][jk] * Vs[s][i]
  int lane = tid & 63, jg = tid >> 6;
  float acc[16];
#pragma unroll
  for (int q = 0; q < 16; q++) acc[q] = 0.f;
  for (int s = 0; s < 64; s++) {
    float vi = Vs[s * 64 + lane];
#pragma unroll
    for (int q4 = 0; q4 < 4; q4++) {
      float4 kk = *(const float4*)(Ks + s * 64 + jg * 16 + q4 * 4);
      acc[q4 * 4 + 0] = fmaf(kk.x, vi, acc[q4 * 4 + 0]);
      acc[q4 * 4 + 1] = fmaf(kk.y, vi, acc[q4 * 4 + 1]);
      acc[q4 * 4 + 2] = fmaf(kk.z, vi, acc[q4 * 4 + 2]);
      acc[q4 * 4 + 3] = fmaf(kk.w, vi, acc[q4 * 4 + 3]);
    }
  }
  float* out = kvb + ((long)bh * nch + c) * 4096;
#pragma unroll
  for (int q = 0; q < 16; q++) out[(jg * 16 + q) * 64 + lane] = acc[q];
}

// ---------------------------------------- chunked WKV: state prefix scan ---
__global__ __launch_bounds__(256) void k_wkv_scan(
    const float* __restrict__ kvb, const float* __restrict__ aL,
    float* __restrict__ Scb, int nch) {
  int bh = blockIdx.x >> 4;
  int e = ((blockIdx.x & 15) << 8) + threadIdx.x;   // 0..4095
  float S = 0.f;
  for (int c = 0; c < nch; c++) {
    long cb = ((long)bh * nch + c) * 4096 + e;
    Scb[cb] = S;
    S = aL[((long)bh * nch + c) * 64 + (e >> 6)] * (S + kvb[cb]);
  }
}

// ------------- chunked WKV: intra + inter + groupnorm*gate (fused) ---------
// Pre-phase recomputes rt/kt from r,k,w (same two-level prefix as prekv) and
// writes KtT/RtT [chan][time] DIRECTLY (no global rt/kt, no reg-transpose
// stage). pdiag computed block-locally via Pt scratch. Then R16's
// outer-product phase1 + fused pass + GN.
__global__ __launch_bounds__(256, 3) void k_wkv_intra(
    const float* __restrict__ r, const float* __restrict__ k,
    const float* __restrict__ w, const float* __restrict__ u,
    const float* __restrict__ v, const float* __restrict__ Scb,
    const float* __restrict__ g,
    const float* __restrict__ ln_w, const float* __restrict__ ln_b,
    ushort* __restrict__ z, int B, int T, int C, int H, int L) {
  int nch = T / L;
  int blk = blockIdx.x;
  int bh = blk / nch, c = blk - bh * nch;
  int b = bh / H, h = bh - b * H;
  __shared__ float KtT[64 * 68];   // [chan][time]
  __shared__ float RtT[64 * 68];   // [chan][time] (also passB operand)
  __shared__ float Pt[64 * 68];    // pls scratch -> P^T [s][tau]
  __shared__ float gsum[4 * 64];
  __shared__ float pdv[64];
  int tid = threadIdx.x;
  int lane = tid & 63, wid = tid >> 6;
  long cbase = ((long)b * T + (long)c * L) * C + h * 64;
  const float* scp = Scb + ((long)bh * nch + c) * 4096;

  // --- pre: two-level prefix; write rt/kt transposed; pls into Pt ---
  {
    int gsel = wid;                // tau group (16 taus)
    int j = lane;                  // channel
    int tau0p = gsel * 16;
    float uj = u[h * 64 + j];
    float ev[16];
#pragma unroll
    for (int i = 0; i < 16; i++)
      ev[i] = expf(w[cbase + (long)(tau0p + i) * C + j]);
    float pre[16];
    float run = 0.f;
#pragma unroll
    for (int i = 0; i < 16; i++) { pre[i] = run; run += ev[i]; }
    gsum[gsel * 64 + j] = run;
    __syncthreads();                                         // b0
    float off0 = (gsel > 0 ? gsum[j] : 0.f) +
                 (gsel > 1 ? gsum[64 + j] : 0.f) +
                 (gsel > 2 ? gsum[128 + j] : 0.f);
#pragma unroll
    for (int i = 0; i < 16; i++) {
      int tau = tau0p + i;
      long offg = cbase + (long)tau * C + j;
      float rv = r[offg];
      float kv = k[offg];
      float ce = off0 + pre[i];
      RtT[j * 68 + tau] = rv * expf(-ce);
      KtT[j * 68 + tau] = kv * expf(ce + ev[i]);
      Pt[tau * 68 + j] = rv * uj * kv;
    }
  }
  __syncthreads();                                           // b1
  if (tid < 64) {
    float s0 = 0.f, s1 = 0.f, s2 = 0.f, s3 = 0.f;
#pragma unroll
    for (int q = 0; q < 16; q++) {
      float4 p4 = *(const float4*)(Pt + tid * 68 + q * 4);
      s0 += p4.x; s1 += p4.y; s2 += p4.z; s3 += p4.w;
    }
    pdv[tid] = (s0 + s1) + (s2 + s3);
  }
  __syncthreads();                                           // b2

  // --- phase 1: outer-product P^T[s0..3][tau0..3] ---
  {
    int s0 = (tid >> 4) * 4;
    int tau0 = (tid & 15) * 4;
    float4 pd4 = *(const float4*)(pdv + tau0);
    float p00 = 0.f, p01 = 0.f, p02 = 0.f, p03 = 0.f;
    float p10 = 0.f, p11 = 0.f, p12 = 0.f, p13 = 0.f;
    float p20 = 0.f, p21 = 0.f, p22 = 0.f, p23 = 0.f;
    float p30 = 0.f, p31 = 0.f, p32 = 0.f, p33 = 0.f;
#pragma unroll 4
    for (int cc = 0; cc < 64; cc++) {
      float4 kq = *(const float4*)(KtT + cc * 68 + s0);
      float4 rq = *(const float4*)(RtT + cc * 68 + tau0);
      p00 = fmaf(kq.x, rq.x, p00); p01 = fmaf(kq.x, rq.y, p01);
      p02 = fmaf(kq.x, rq.z, p02); p03 = fmaf(kq.x, rq.w, p03);
      p10 = fmaf(kq.y, rq.x, p10); p11 = fmaf(kq.y, rq.y, p11);
      p12 = fmaf(kq.y, rq.z, p12); p13 = fmaf(kq.y, rq.w, p13);
      p20 = fmaf(kq.z, rq.x, p20); p21 = fmaf(kq.z, rq.y, p21);
      p22 = fmaf(kq.z, rq.z, p22); p23 = fmaf(kq.z, rq.w, p23);
      p30 = fmaf(kq.w, rq.x, p30); p31 = fmaf(kq.w, rq.y, p31);
      p32 = fmaf(kq.w, rq.z, p32); p33 = fmaf(kq.w, rq.w, p33);
    }
#define PMASK(PI0, PI1, PI2, PI3, I)                                       \
    {                                                                      \
      int s = s0 + (I);                                                    \
      float4 o;                                                            \
      o.x = (s < tau0 + 0) ? PI0 : (s == tau0 + 0 ? pd4.x : 0.f);          \
      o.y = (s < tau0 + 1) ? PI1 : (s == tau0 + 1 ? pd4.y : 0.f);          \
      o.z = (s < tau0 + 2) ? PI2 : (s == tau0 + 2 ? pd4.z : 0.f);          \
      o.w = (s < tau0 + 3) ? PI3 : (s == tau0 + 3 ? pd4.w : 0.f);          \
      *(float4*)(Pt + s * 68 + tau0) = o;                                  \
    }
    PMASK(p00, p01, p02, p03, 0)
    PMASK(p10, p11, p12, p13, 1)
    PMASK(p20, p21, p22, p23, 2)
    PMASK(p30, p31, p32, p33, 3)
#undef PMASK
  }
  __syncthreads();                                           // b3

  // --- fused pass: Y = P^T(row0..3) . V  +  RtT(row0..3) . S ---
  int row0 = wid * 16 + ((lane >> 4) << 2);   // 4 output taus
  int c0v = (lane & 15) * 4;                  // 4 output chans
  float4 acc0 = {0.f, 0.f, 0.f, 0.f};
  float4 acc1 = {0.f, 0.f, 0.f, 0.f};
  float4 acc2 = {0.f, 0.f, 0.f, 0.f};
  float4 acc3 = {0.f, 0.f, 0.f, 0.f};
  const float* vp = v + cbase + c0v;
#define FMA2(A, P, V4, R, S4)                          \
  A.x = fmaf(P, V4.x, fmaf(R, S4.x, A.x));             \
  A.y = fmaf(P, V4.y, fmaf(R, S4.y, A.y));             \
  A.z = fmaf(P, V4.z, fmaf(R, S4.z, A.z));             \
  A.w = fmaf(P, V4.w, fmaf(R, S4.w, A.w));
#pragma unroll 4
  for (int j = 0; j < 64; j++) {
    float4 pp = *(const float4*)(Pt + j * 68 + row0);    // 16-lane multicast
    float4 rr = *(const float4*)(RtT + j * 68 + row0);   // 16-lane multicast
    float4 vv = *(const float4*)(vp + (long)j * C);      // L2, 256B/wave
    float4 ssv = *(const float4*)(scp + j * 64 + c0v);   // L2, 256B/wave
    FMA2(acc0, pp.x, vv, rr.x, ssv);
    FMA2(acc1, pp.y, vv, rr.y, ssv);
    FMA2(acc2, pp.z, vv, rr.z, ssv);
    FMA2(acc3, pp.w, vv, rr.w, ssv);
  }
#undef FMA2

  // ---- fused groupnorm (per row over this head's 64 channels) * gate ----
  float4 lw4 = *(const float4*)(ln_w + h * 64 + c0v);
  float4 lb4 = *(const float4*)(ln_b + h * 64 + c0v);
#define GNROW(A, m)                                                        \
  {                                                                        \
    float s1 = (A.x + A.y) + (A.z + A.w);                                  \
    s1 += __shfl_xor(s1, 1, 64);                                           \
    s1 += __shfl_xor(s1, 2, 64);                                           \
    s1 += __shfl_xor(s1, 4, 64);                                           \
    s1 += __shfl_xor(s1, 8, 64);                                           \
    float mu = s1 * (1.f / 64.f);                                          \
    float4 dd;                                                             \
    dd.x = A.x - mu; dd.y = A.y - mu; dd.z = A.z - mu; dd.w = A.w - mu;    \
    float s2 = (dd.x * dd.x + dd.y * dd.y) + (dd.z * dd.z + dd.w * dd.w);  \
    s2 += __shfl_xor(s2, 1, 64);                                           \
    s2 += __shfl_xor(s2, 2, 64);                                           \
    s2 += __shfl_xor(s2, 4, 64);                                           \
    s2 += __shfl_xor(s2, 8, 64);                                           \
    float rstd = rsqrtf(s2 * (1.f / 64.f) + 1e-5f);                        \
    long off = cbase + (long)(row0 + m) * C + c0v;                         \
    float4 g4 = *(const float4*)(g + off);                                 \
    ushort4 ob;                                                            \
    ob.x = f2bf((dd.x * rstd * lw4.x + lb4.x) * g4.x);                     \
    ob.y = f2bf((dd.y * rstd * lw4.y + lb4.y) * g4.y);                     \
    ob.z = f2bf((dd.z * rstd * lw4.z + lb4.z) * g4.z);                     \
    ob.w = f2bf((dd.w * rstd * lw4.w + lb4.w) * g4.w);                     \
    *(ushort4*)(z + off) = ob;                                             \
  }
  GNROW(acc0, 0)
  GNROW(acc1, 1)
  GNROW(acc2, 2)
  GNROW(acc3, 3)
#undef GNROW
}

// ---------------------------------------------------------------- launch ---
extern "C" void kernel_launch(void* const* d_in, const int* in_sizes, int n_in,
                              void* d_out, int out_size, void* d_ws, size_t ws_size,
                              hipStream_t stream) {
  const int B = 8, T = 1024, C = 768, H = 12, ph = 32, pw = 32;
  const int M = B * T;
  const int L = 64, NCH = T / L;

  const float* x        = (const float*)d_in[0];
  const float* W_r      = (const float*)d_in[1];
  const float* W_k      = (const float*)d_in[2];
  const float* W_v      = (const float*)d_in[3];
  const float* W_g      = (const float*)d_in[4];
  const float* W_o      = (const float*)d_in[5];
  const float* maa_x    = (const float*)d_in[6];
  const float* maa_w    = (const float*)d_in[7];
  const float* maa_k    = (const float*)d_in[8];
  const float* maa_v    = (const float*)d_in[9];
  const float* maa_r    = (const float*)d_in[10];
  const float* maa_g    = (const float*)d_in[11];
  const float* maa_w1   = (const float*)d_in[12];
  const float* maa_w2   = (const float*)d_in[13];
  const float* time_dec = (const float*)d_in[14];
  const float* dec_w1   = (const float*)d_in[15];
  const float* dec_w2   = (const float*)d_in[16];
  const float* faaaa    = (const float*)d_in[17];
  const float* ln_w     = (const float*)d_in[18];
  const float* ln_b     = (const float*)d_in[19];

  float* ws = (float*)d_ws;
  const size_t S = (size_t)M * C;
  float* F0 = ws + 0 * S;   // r (fp32)
  float* F1 = ws + 1 * S;   // xxx_bf -> k (fp32, lives through intra)
  float* F2 = ws + 2 * S;   // xw_bf -> w (fp32, lives through intra)
  float* F3 = ws + 3 * S;   // v (fp32)
  float* F4 = ws + 4 * S;   // g (fp32)
  float* F5 = ws + 5 * S;   // xr_bf | xk_bf -> Scb
  float* F6 = ws + 6 * S;   // xv_bf | xg_bf -> kvb -> z_bf
  float* t5    = ws + 7 * S;            // [M,160] bf16 t5b -> bf16 W_r..W_g
  float* t6    = t5 + (size_t)M * 160;  // bf16 W_o + maa1T + decT
  float* aLb   = t6 + (size_t)M * 64;
  float* pdiag = aLb + (size_t)B * H * NCH * 64;   // (unused, kept for layout)
  float* dec_t = pdiag + (size_t)B * H * T;        // [M,64] t_bf + w2T scratch

  ushort* xxx_bf = (ushort*)F1;
  ushort* xw_bf = (ushort*)F2;
  ushort* xr_bf = (ushort*)F5;
  ushort* xk_bf = xr_bf + S;
  ushort* xv_bf = (ushort*)F6;
  ushort* xg_bf = xv_bf + S;
  float*  kvb   = F6;                   // dead xv/xg space; dead after scan
  ushort* z_bf  = (ushort*)F6;          // intra output (after scan)
  float*  Scb   = F5;                   // dead xr/xk space (after proj4)
  ushort* t5b   = (ushort*)t5;          // [M,160] bf16
  ushort* t_bf  = (ushort*)dec_t;       // [M,64] bf16
  ushort* w2T   = t_bf + (size_t)M * 64;  // [768,160] bf16 (dead after mix5)
  const int WSZ = C * C;
  ushort* wr_bf = (ushort*)t5;
  ushort* wk_bf = wr_bf + WSZ;
  ushort* wv_bf = wk_bf + WSZ;
  ushort* wg_bf = wv_bf + WSZ;
  ushort* wo_bf = (ushort*)t6;
  ushort* maa1T = wo_bf + WSZ;          // [256,768]
  ushort* w1dT  = maa1T + 256 * 768;    // [128,768]
  ushort* w2dT  = w1dT + 128 * 768;     // [768,64]

  // 1. fused qshift + weight transposes (one launch)
  {
    k_prep<<<24576 + 1824, 256, 0, stream>>>(
        x, maa_x, xxx_bf, maa_w1, maa_w2, dec_w1, dec_w2,
        maa1T, w2T, w1dT, w2dT, B, T, C, ph, pw);
  }
  // 2. t5b = tanh(xxx @ maa_w1) via MFMA (bf16 out)
  {
    dim3 grid(2, M / 128);
    k_gemm_bf<EPI_TANH, true, true><<<grid, 256, 0, stream>>>(
        xxx_bf, maa1T, nullptr, t5b, M, 160, C);
  }
  // 3. mix5 on MFMA (all outputs bf16; dh inline)
  {
    dim3 grid(C / 128, M / 64);
    k_mix5m<<<grid, 256, 0, stream>>>(t5b, w2T, x, maa_w, maa_k, maa_v,
                                      maa_r, maa_g, xw_bf, xk_bf, xv_bf, xr_bf,
                                      xg_bf, C, T, ph, pw);
  }
  // 4. weight conversion (t5b data dead now)
  {
    dim3 grid((WSZ / 4 + 255) / 256, 5);
    k_cvt5<<<grid, 256, 0, stream>>>(W_r, W_k, W_v, W_g, W_o,
                                     wr_bf, wk_bf, wv_bf, wg_bf, wo_bf, WSZ);
  }
  // 5. big projections (r,k,v,g fp32) + decay-1 (t_bf) — 1600 blocks, 1D
  {
    k_proj4<<<(C / 128) * (M / 128) * 4 + (M / 128), 256, 0, stream>>>(
        xr_bf, xk_bf, xv_bf, xg_bf, xw_bf,
        wr_bf, wk_bf, wv_bf, wg_bf, w1dT,
        F0, F1, F3, F4, t_bf, M, C, C);
  }
  // 6. decay-2: w = time_dec + t_bf @ w2dT (fp32 into F2; xw dead now)
  {
    dim3 g2(C / 128, M / 128);
    k_gemm_bf<EPI_BIAS, false, false><<<g2, 256, 0, stream>>>(
        t_bf, w2dT, time_dec, F2, M, C, 64);
  }
  // 7. chunked wkv6: prekv(slim) -> scan -> intra(prefix+GN+gate -> z bf16)
  k_wkv_prekv<<<B * H * NCH, 256, 0, stream>>>(
      F1, F2, F3, aLb, kvb, B, T, C, H, L);
  k_wkv_scan<<<B * H * 16, 256, 0, stream>>>(kvb, aLb, Scb, NCH);
  k_wkv_intra<<<B * H * NCH, 256, 0, stream>>>(
      F0, F1, F2, faaaa, F3, Scb, F4, ln_w, ln_b, z_bf, B, T, C, H, L);
  // 8. out = z @ W_o^T (bf16 MFMA)
  {
    dim3 grid(C / 128, M / 128);
    k_gemm_bf<EPI_NONE, false, false><<<grid, 256, 0, stream>>>(
        z_bf, wo_bf, nullptr, (float*)d_out, M, C, C);
  }
}